// Round 7
// baseline (975.903 us; speedup 1.0000x reference)
//
#include <hip/hip_runtime.h>
#include <hip/hip_cooperative_groups.h>

namespace cg = cooperative_groups;

#define IN_CH 128
#define HEADS 4
#define OUT_CH 32
#define HC 128           // HEADS*OUT_CH
#define SCORE_BLOCKS 4096
#define CHUNK 2048       // scan chunk (256 thr x 8)

__device__ __forceinline__ unsigned flip_f32(float x) {
  unsigned u = __float_as_uint(x);
  return (u & 0x80000000u) ? ~u : (u | 0x80000000u);
}
__device__ __forceinline__ float unflip_f32(unsigned k) {
  unsigned u = (k & 0x80000000u) ? (k ^ 0x80000000u) : ~k;
  return __uint_as_float(u);
}
// tanh(x) = 1 - 2/(e^{2x}+1); e^{2x} = 2^{x * 2*log2(e)} -> single v_exp_f32
__device__ __forceinline__ float fast_tanh(float x) {
#if __has_builtin(__builtin_amdgcn_exp2f)
  const float t = __builtin_amdgcn_exp2f(x * 2.8853900817779268f);
#else
  const float t = __expf(2.f * x);
#endif
  return 1.f - 2.f / (t + 1.f);
}

// proj[N][128] = x[N][128] @ W[128][128], 64x64 tiles -> 69.6KB LDS
// -> 2 blocks/CU (8 waves/CU); plus fused edge-histogram tail.
__global__ __launch_bounds__(256) void gemm_xW(const float* __restrict__ x,
                                               const float* __restrict__ W,
                                               float* __restrict__ proj, int N,
                                               const int* __restrict__ ecol,
                                               int* __restrict__ hist, int E) {
  __shared__ float xs[128][68];  // [k][r]
  __shared__ float ws[128][68];  // [k][c]
  const int tid = threadIdx.x;
  const int rowblk = blockIdx.x >> 1;
  const int colblk = blockIdx.x & 1;
  const int row0 = rowblk * 64;
  const int col0 = colblk * 64;

  {
    const int k = tid >> 1;
    const int c0 = (tid & 1) * 32;
    const float4* src = (const float4*)(W + (size_t)k * HC + col0 + c0);
#pragma unroll
    for (int i = 0; i < 8; ++i) *(float4*)&ws[k][c0 + i * 4] = src[i];
  }
  {
    const int r = tid >> 2;
    const int k0 = (tid & 3) * 32;
    const int grow = row0 + r;
    const bool valid = grow < N;
    const float4* src = (const float4*)(x + (size_t)grow * IN_CH + k0);
#pragma unroll
    for (int i = 0; i < 8; ++i) {
      float4 v = valid ? src[i] : make_float4(0.f, 0.f, 0.f, 0.f);
      const int k = k0 + i * 4;
      xs[k][r] = v.x; xs[k + 1][r] = v.y; xs[k + 2][r] = v.z; xs[k + 3][r] = v.w;
    }
  }
  __syncthreads();

  const int cg2 = tid & 15;
  const int rg = tid >> 4;
  float acc[4][4];
#pragma unroll
  for (int r = 0; r < 4; ++r)
#pragma unroll
    for (int c = 0; c < 4; ++c) acc[r][c] = 0.f;

#pragma unroll 8
  for (int k = 0; k < 128; ++k) {
    const float4 a = *(const float4*)&xs[k][rg * 4];
    const float4 b = *(const float4*)&ws[k][cg2 * 4];
    const float xv[4] = {a.x, a.y, a.z, a.w};
    const float wv[4] = {b.x, b.y, b.z, b.w};
#pragma unroll
    for (int r = 0; r < 4; ++r)
#pragma unroll
      for (int c = 0; c < 4; ++c) acc[r][c] += xv[r] * wv[c];
  }

#pragma unroll
  for (int r = 0; r < 4; ++r) {
    const int grow = row0 + rg * 4 + r;
    if (grow < N) {
      *(float4*)(proj + (size_t)grow * HC + col0 + cg2 * 4) =
          make_float4(acc[r][0], acc[r][1], acc[r][2], acc[r][3]);
    }
  }

  if (hist) {
    const int ehb = (E + gridDim.x - 1) / gridDim.x;
    const int estart = blockIdx.x * ehb;
    const int eend = min(estart + ehb, E);
    for (int e = estart + tid; e < eend; e += 256) atomicAdd(&hist[ecol[e]], 1);
  }
}

__device__ __forceinline__ int block_scan_excl(int tsum, int* ls, int tid, int* total) {
  ls[tid] = tsum;
  __syncthreads();
  for (int off = 1; off < 256; off <<= 1) {
    int v = (tid >= off) ? ls[tid - off] : 0;
    __syncthreads();
    ls[tid] += v;
    __syncthreads();
  }
  *total = ls[255];
  return ls[tid] - tsum;
}

// ONE cooperative kernel: scan -> prefix+starts/cursor -> scatter -> apply -> clamp.
// Eliminates 4 inter-dispatch gaps; apply phase is persistent-wave with next-node
// prefetch (starts + d4 issued before the current node's edge loop).
__global__ __launch_bounds__(256, 4) void csr_apply_coop(
    const float* __restrict__ proj, const int* __restrict__ hist,
    int* __restrict__ sums, int* __restrict__ starts, int* __restrict__ cursor,
    int* __restrict__ rc, const int* __restrict__ erow, const int* __restrict__ ecol,
    const float* __restrict__ att, float* __restrict__ out, float* __restrict__ den,
    unsigned* __restrict__ headmax_u, int N, int E, int nc) {
  cg::grid_group grid = cg::this_grid();
  __shared__ int ls[256];
  __shared__ unsigned blkmax[HEADS];
  const int tid = threadIdx.x;
  const int bid = blockIdx.x;
  const int nblk = gridDim.x;

  // ---- phase 1: per-chunk scan (blocks 0..nc-1) ----
  int h0=0,h1=0,h2=0,h3=0,h4=0,h5=0,h6=0,h7=0;
  int excl = 0, total = 0;
  if (bid < nc) {
    const int base = bid * CHUNK + tid * 8;
    if (base + 7 < N) {
      h0=hist[base];   h1=hist[base+1]; h2=hist[base+2]; h3=hist[base+3];
      h4=hist[base+4]; h5=hist[base+5]; h6=hist[base+6]; h7=hist[base+7];
    } else {
      if (base < N)     h0=hist[base];
      if (base+1 < N)   h1=hist[base+1];
      if (base+2 < N)   h2=hist[base+2];
      if (base+3 < N)   h3=hist[base+3];
      if (base+4 < N)   h4=hist[base+4];
      if (base+5 < N)   h5=hist[base+5];
      if (base+6 < N)   h6=hist[base+6];
      if (base+7 < N)   h7=hist[base+7];
    }
    const int t = ((h0+h1)+(h2+h3)) + ((h4+h5)+(h6+h7));
    excl = block_scan_excl(t, ls, tid, &total);
    if (tid == 0) sums[bid] = total;
  }
  __threadfence();
  grid.sync();

  // ---- phase 2: chunk prefix + write starts/cursor ----
  if (bid < nc) {
    int cbase = 0;
    for (int j = 0; j < bid; ++j) cbase += sums[j];
    int run = cbase + excl;
    const int base = bid * CHUNK + tid * 8;
    const int hs[8] = {h0,h1,h2,h3,h4,h5,h6,h7};
#pragma unroll
    for (int j = 0; j < 8; ++j) {
      const int i = base + j;
      if (i < N) { starts[i] = run; cursor[i] = run; run += hs[j]; }
    }
    if (bid == nc - 1 && tid == 0) {
      starts[N] = cbase + total;
      cursor[N] = cbase + total;
    }
  }
  __threadfence();
  grid.sync();

  // ---- phase 3: scatter rc (pre-scaled row*HC) ----
  for (int i = bid * 256 + tid; i < E; i += nblk * 256) {
    const int p = atomicAdd(&cursor[ecol[i]], 1);
    rc[p] = erow[i] * HC;
  }
  __threadfence();
  grid.sync();

  // ---- phase 4: persistent-wave apply ----
  if (tid < HEADS) blkmax[tid] = 0u;
  __syncthreads();
  {
    const int lane = tid & 63;
    const int half = lane >> 5;
    const int l = lane & 31;
    const int c0 = l * 4;
    const int head = l >> 3;
    const int GW = nblk * 4;
    const float4 a4 = ((const float4*)att)[l];
    float M0 = fabsf(a4.x) + fabsf(a4.y) + fabsf(a4.z) + fabsf(a4.w);
    M0 += __shfl_xor(M0, 4, 64);
    M0 += __shfl_xor(M0, 2, 64);
    M0 += __shfl_xor(M0, 1, 64);

    int n = bid * 4 + (tid >> 6);
    int nbg = 0, neg = 0;
    float4 d4 = make_float4(0.f, 0.f, 0.f, 0.f);
    if (n < N) {
      nbg = starts[n]; neg = starts[n + 1];
      d4 = *(const float4*)(proj + (size_t)n * HC + c0);
    }
    while (n < N) {
      // prefetch next node's range + dst row (hides latency under edge loop)
      const int n2 = n + GW;
      int nb2 = 0, ne2 = 0;
      float4 d42 = make_float4(0.f, 0.f, 0.f, 0.f);
      if (n2 < N) {
        nb2 = starts[n2]; ne2 = starts[n2 + 1];
        d42 = *(const float4*)(proj + (size_t)n2 * HC + c0);
      }
      const int beg = __builtin_amdgcn_readfirstlane(nbg);
      const int end = __builtin_amdgcn_readfirstlane(neg);
      float lm = -3.0e38f;
      float ax = 0.f, ay = 0.f, az = 0.f, aw = 0.f, dsum = 0.f;
      int i = beg;
      for (; i + 8 <= end; i += 8) {
        const int r0 = rc[i + half];
        const int r1 = rc[i + 2 + half];
        const int r2 = rc[i + 4 + half];
        const int r3 = rc[i + 6 + half];
        const float4 s0 = *(const float4*)(proj + r0 + c0);
        const float4 s1 = *(const float4*)(proj + r1 + c0);
        const float4 s2 = *(const float4*)(proj + r2 + c0);
        const float4 s3 = *(const float4*)(proj + r3 + c0);
        float p0 = fast_tanh(s0.x + d4.x) * a4.x + fast_tanh(s0.y + d4.y) * a4.y
                 + fast_tanh(s0.z + d4.z) * a4.z + fast_tanh(s0.w + d4.w) * a4.w;
        float p1 = fast_tanh(s1.x + d4.x) * a4.x + fast_tanh(s1.y + d4.y) * a4.y
                 + fast_tanh(s1.z + d4.z) * a4.z + fast_tanh(s1.w + d4.w) * a4.w;
        float p2 = fast_tanh(s2.x + d4.x) * a4.x + fast_tanh(s2.y + d4.y) * a4.y
                 + fast_tanh(s2.z + d4.z) * a4.z + fast_tanh(s2.w + d4.w) * a4.w;
        float p3 = fast_tanh(s3.x + d4.x) * a4.x + fast_tanh(s3.y + d4.y) * a4.y
                 + fast_tanh(s3.z + d4.z) * a4.z + fast_tanh(s3.w + d4.w) * a4.w;
        p0 += __shfl_xor(p0, 4, 64);  p1 += __shfl_xor(p1, 4, 64);
        p2 += __shfl_xor(p2, 4, 64);  p3 += __shfl_xor(p3, 4, 64);
        p0 += __shfl_xor(p0, 2, 64);  p1 += __shfl_xor(p1, 2, 64);
        p2 += __shfl_xor(p2, 2, 64);  p3 += __shfl_xor(p3, 2, 64);
        p0 += __shfl_xor(p0, 1, 64);  p1 += __shfl_xor(p1, 1, 64);
        p2 += __shfl_xor(p2, 1, 64);  p3 += __shfl_xor(p3, 1, 64);
        lm = fmaxf(lm, fmaxf(fmaxf(p0, p1), fmaxf(p2, p3)));
        const float e0 = __expf(p0 - M0);
        const float e1 = __expf(p1 - M0);
        const float e2 = __expf(p2 - M0);
        const float e3 = __expf(p3 - M0);
        ax += s0.x * e0 + s1.x * e1 + s2.x * e2 + s3.x * e3;
        ay += s0.y * e0 + s1.y * e1 + s2.y * e2 + s3.y * e3;
        az += s0.z * e0 + s1.z * e1 + s2.z * e2 + s3.z * e3;
        aw += s0.w * e0 + s1.w * e1 + s2.w * e2 + s3.w * e3;
        dsum += (e0 + e1) + (e2 + e3);
      }
      if (i + 4 <= end) {
        const int r0 = rc[i + half];
        const int r1 = rc[i + 2 + half];
        const float4 s0 = *(const float4*)(proj + r0 + c0);
        const float4 s1 = *(const float4*)(proj + r1 + c0);
        float p0 = fast_tanh(s0.x + d4.x) * a4.x + fast_tanh(s0.y + d4.y) * a4.y
                 + fast_tanh(s0.z + d4.z) * a4.z + fast_tanh(s0.w + d4.w) * a4.w;
        float p1 = fast_tanh(s1.x + d4.x) * a4.x + fast_tanh(s1.y + d4.y) * a4.y
                 + fast_tanh(s1.z + d4.z) * a4.z + fast_tanh(s1.w + d4.w) * a4.w;
        p0 += __shfl_xor(p0, 4, 64);  p1 += __shfl_xor(p1, 4, 64);
        p0 += __shfl_xor(p0, 2, 64);  p1 += __shfl_xor(p1, 2, 64);
        p0 += __shfl_xor(p0, 1, 64);  p1 += __shfl_xor(p1, 1, 64);
        lm = fmaxf(lm, fmaxf(p0, p1));
        const float e0 = __expf(p0 - M0);
        const float e1 = __expf(p1 - M0);
        ax += s0.x * e0 + s1.x * e1;
        ay += s0.y * e0 + s1.y * e1;
        az += s0.z * e0 + s1.z * e1;
        aw += s0.w * e0 + s1.w * e1;
        dsum += e0 + e1;
        i += 4;
      }
      for (; i < end; i += 2) {
        const int idx = i + half;
        const bool valid = idx < end;
        const int row = rc[valid ? idx : i];
        const float4 s4 = *(const float4*)(proj + row + c0);
        float p = fast_tanh(s4.x + d4.x) * a4.x
                + fast_tanh(s4.y + d4.y) * a4.y
                + fast_tanh(s4.z + d4.z) * a4.z
                + fast_tanh(s4.w + d4.w) * a4.w;
        p += __shfl_xor(p, 4, 64);
        p += __shfl_xor(p, 2, 64);
        p += __shfl_xor(p, 1, 64);
        if (!valid) p = -3.0e38f;
        lm = fmaxf(lm, p);
        const float e = __expf(p - M0);
        ax += s4.x * e; ay += s4.y * e; az += s4.z * e; aw += s4.w * e;
        dsum += e;
      }
      dsum += __shfl_xor(dsum, 32, 64);
      ax += __shfl_xor(ax, 32, 64);
      ay += __shfl_xor(ay, 32, 64);
      az += __shfl_xor(az, 32, 64);
      aw += __shfl_xor(aw, 32, 64);
      lm = fmaxf(lm, __shfl_xor(lm, 32, 64));
      if (half == 0) {
        const float inv = 1.f / fmaxf(dsum, 1e-38f);
        *(float4*)(out + (size_t)n * HC + c0) =
            make_float4(ax * inv, ay * inv, az * inv, aw * inv);
        if ((l & 7) == 0) {
          den[n * HEADS + head] = dsum;
          atomicMax(&blkmax[head], flip_f32(lm));
        }
      }
      n = n2; nbg = nb2; neg = ne2; d4 = d42;
    }
  }
  __syncthreads();
  if (tid < HEADS) atomicMax(&headmax_u[tid], blkmax[tid]);
  __threadfence();
  grid.sync();

  // ---- phase 5: clamp fix (reference's max(norm,1e-12) semantics) ----
  for (int t = bid * 256 + tid; t < N * HEADS; t += nblk * 256) {
    const int n = t >> 2;
    const int hh = t & 3;
    float M0h = 0.f;
#pragma unroll
    for (int c = 0; c < OUT_CH; ++c) M0h += fabsf(att[hh * OUT_CH + c]);
    const float Mt = unflip_f32(headmax_u[hh]);
    const float f = den[t] * __expf(M0h - Mt);
    if (f < 1e-12f) {
      const float s = f * 1e12f;
      float4* pp = (float4*)(out + (size_t)n * HC + hh * OUT_CH);
#pragma unroll
      for (int j = 0; j < 8; ++j) {
        float4 v = pp[j];
        v.x *= s; v.y *= s; v.z *= s; v.w *= s;
        pp[j] = v;
      }
    }
  }
}

// blockmax -> corr (fallback path only)
__global__ __launch_bounds__(256) void reduce_corr(const unsigned* __restrict__ blockmax,
                                                   const float* __restrict__ att,
                                                   float* __restrict__ corr, int nblk) {
  __shared__ unsigned sm[HEADS];
  const int tid = threadIdx.x;
  if (tid < HEADS) sm[tid] = 0u;
  __syncthreads();
  const int h = tid & 3;
  unsigned k = 0u;
  for (int i = tid >> 2; i < nblk; i += 64) k = max(k, blockmax[i * HEADS + h]);
  atomicMax(&sm[h], k);
  __syncthreads();
  if (tid < HEADS) {
    const float Mt = unflip_f32(sm[tid]);
    float M0 = 0.f;
#pragma unroll
    for (int c = 0; c < OUT_CH; ++c) M0 += fabsf(att[tid * OUT_CH + c]);
    corr[tid] = __expf(M0 - Mt);
    corr[4 + tid] = Mt;
  }
}

// --- fallback path (ws too small): score-max pass + edge-parallel atomics ---
__global__ __launch_bounds__(256) void score_max(const float* __restrict__ proj,
                                                 const int* __restrict__ erow,
                                                 const int* __restrict__ ecol,
                                                 const float* __restrict__ att,
                                                 unsigned* __restrict__ blockmax, int E) {
  __shared__ unsigned blkmax[HEADS];
  const int tid = threadIdx.x;
  if (tid < HEADS) blkmax[tid] = 0u;
  __syncthreads();
  const int lane = tid & 63;
  const int wid = tid >> 6;
  const float a0 = att[lane];
  const float a1 = att[lane + 64];
  float lmA = -3.0e38f, lmB = -3.0e38f;
  const int stride = SCORE_BLOCKS * 16;

  for (int base = (blockIdx.x * 4 + wid) * 4; base < E; base += stride) {
    const int bu = __builtin_amdgcn_readfirstlane(base);
    const int lim = min(bu + 4, E);
    for (int e = bu; e < lim; ++e) {
      const int r0 = erow[e], c0 = ecol[e];
      const float* ps = proj + (size_t)r0 * HC;
      const float* pd = proj + (size_t)c0 * HC;
      float pA = fast_tanh(ps[lane] + pd[lane]) * a0;
      float pB = fast_tanh(ps[lane + 64] + pd[lane + 64]) * a1;
#pragma unroll
      for (int m = 16; m >= 1; m >>= 1) {
        pA += __shfl_xor(pA, m, 64);
        pB += __shfl_xor(pB, m, 64);
      }
      lmA = fmaxf(lmA, pA);
      lmB = fmaxf(lmB, pB);
    }
  }
  if ((lane & 31) == 0) {
    const int hh = lane >> 5;
    atomicMax(&blkmax[hh], flip_f32(lmA));
    atomicMax(&blkmax[hh + 2], flip_f32(lmB));
  }
  __syncthreads();
  if (tid < HEADS) blockmax[blockIdx.x * HEADS + tid] = blkmax[tid];
}

__global__ __launch_bounds__(256) void edge_apply_fb(const float* __restrict__ proj,
                                                     const int* __restrict__ erow,
                                                     const int* __restrict__ ecol,
                                                     const float* __restrict__ att,
                                                     const float* __restrict__ headmax,
                                                     float* __restrict__ out,
                                                     float* __restrict__ norm, int E) {
  const int tid = threadIdx.x;
  const int e = blockIdx.x * 2 + (tid >> 7);
  if (e >= E) return;
  const int ch = tid & 127;
  const int h = ch >> 5;
  const float M = headmax[h];
  const int row = erow[e];
  const int col = ecol[e];
  const float sv = proj[(size_t)row * HC + ch];
  const float dv = proj[(size_t)col * HC + ch];
  float p = fast_tanh(sv + dv) * att[ch];
#pragma unroll
  for (int m = 16; m >= 1; m >>= 1) p += __shfl_xor(p, m, 64);
  const float w = __expf(p - M);
  unsafeAtomicAdd(&out[(size_t)col * HC + ch], sv * w);
  if ((ch & 31) == 0) unsafeAtomicAdd(&norm[(size_t)col * HEADS + h], w);
}

__global__ __launch_bounds__(256) void finalize_fb(float* __restrict__ out,
                                                   const float* __restrict__ norm, int N) {
  const int idx = blockIdx.x * blockDim.x + threadIdx.x;
  const int total = N * (HC / 4);
  if (idx >= total) return;
  const int base = idx * 4;
  const int node = base >> 7;
  const int h = (base >> 5) & 3;
  const float inv = 1.f / fmaxf(norm[node * HEADS + h], 1e-12f);
  float4 v = ((float4*)out)[idx];
  v.x *= inv; v.y *= inv; v.z *= inv; v.w *= inv;
  ((float4*)out)[idx] = v;
}

extern "C" void kernel_launch(void* const* d_in, const int* in_sizes, int n_in,
                              void* d_out, int out_size, void* d_ws, size_t ws_size,
                              hipStream_t stream) {
  const float* x    = (const float*)d_in[0];
  const int*   eidx = (const int*)d_in[1];  // [2][E]: row(src) then col(dst)
  const float* W    = (const float*)d_in[2];
  const float* att  = (const float*)d_in[3];
  float* out = (float*)d_out;

  const int N = in_sizes[0] / IN_CH;
  const int E = in_sizes[1] / 2;
  const int nb = N;
  const int nc = (nb + CHUNK - 1) / CHUNK;  // scan chunks
  const int ngemm = ((N + 63) / 64) * 2;    // 64-row x 64-col tiles

  // ws layout (16B-aligned pieces)
  char* p = (char*)d_ws;
  float* proj = (float*)p;  p += (size_t)N * HC * 4;
  int* rc = (int*)p;        p += (((size_t)E * 4 + 15) & ~15ull);
  float* den = (float*)p;   p += (((size_t)N * HEADS * 4 + 15) & ~15ull);
  int* hist = (int*)p;      p += (((size_t)(nb + 4) * 4 + 15) & ~15ull);  // +4: headmax_u
  int* starts = (int*)p;    p += (((size_t)(nb + 1) * 4 + 15) & ~15ull);
  int* cursor = (int*)p;    p += (((size_t)(nb + 1) * 4 + 15) & ~15ull);
  int* sums = (int*)p;      p += 4096;
  unsigned* headmax_u = (unsigned*)(hist + nb);
  const size_t need_full = (size_t)(p - (char*)d_ws);

  // cooperative grid sizing (must be co-resident)
  int bpc = 0;
  if (hipOccupancyMaxActiveBlocksPerMultiprocessor(&bpc, csr_apply_coop, 256, 0)
          != hipSuccess || bpc <= 0)
    bpc = 2;
  int gridc = bpc * 256;
  if (gridc > 1024) gridc = 1024;
  const bool full = (ws_size >= need_full) && (nc <= gridc) && (nc <= 1024);

  if (full) {
    hipMemsetAsync(hist, 0, (size_t)(nb + 4) * sizeof(int), stream);  // hist + headmax_u
    gemm_xW<<<ngemm, 256, 0, stream>>>(x, W, proj, N, eidx + E, hist, E);
    const int* erow = eidx;
    const int* ecol = eidx + E;
    int Nv = N, Ev = E, ncv = nc;
    void* args[] = {(void*)&proj, (void*)&hist, (void*)&sums, (void*)&starts,
                    (void*)&cursor, (void*)&rc, (void*)&erow, (void*)&ecol,
                    (void*)&att, (void*)&out, (void*)&den, (void*)&headmax_u,
                    (void*)&Nv, (void*)&Ev, (void*)&ncv};
    hipLaunchCooperativeKernel((void*)csr_apply_coop, dim3(gridc), dim3(256),
                               args, 0, stream);
  } else {
    // minimal-ws fallback: blockmax/corr/norm packed right after proj
    gemm_xW<<<ngemm, 256, 0, stream>>>(x, W, proj, N, nullptr, nullptr, 0);
    unsigned* bm = (unsigned*)(proj + (size_t)N * HC);
    float* cr = (float*)(bm + SCORE_BLOCKS * HEADS);
    float* norm = cr + 8;
    hipMemsetAsync(out, 0, (size_t)out_size * sizeof(float), stream);
    hipMemsetAsync(norm, 0, (size_t)N * HEADS * sizeof(float), stream);
    score_max<<<SCORE_BLOCKS, 256, 0, stream>>>(proj, eidx, eidx + E, att, bm, E);
    reduce_corr<<<1, 256, 0, stream>>>(bm, att, cr, SCORE_BLOCKS);
    edge_apply_fb<<<(E + 1) / 2, 256, 0, stream>>>(proj, eidx, eidx + E, att, cr + 4, out, norm, E);
    finalize_fb<<<(N * (HC / 4) + 255) / 256, 256, 0, stream>>>(out, norm, N);
  }
}

// Round 8
// 453.965 us; speedup vs baseline: 2.1497x; 2.1497x over previous
//
#include <hip/hip_runtime.h>

#define IN_CH 128
#define HEADS 4
#define OUT_CH 32
#define HC 128           // HEADS*OUT_CH
#define SCORE_BLOCKS 4096
#define CHUNK 2048       // scan chunk (256 thr x 8)

__device__ __forceinline__ unsigned flip_f32(float x) {
  unsigned u = __float_as_uint(x);
  return (u & 0x80000000u) ? ~u : (u | 0x80000000u);
}
__device__ __forceinline__ float unflip_f32(unsigned k) {
  unsigned u = (k & 0x80000000u) ? (k ^ 0x80000000u) : ~k;
  return __uint_as_float(u);
}
// tanh(x) = 1 - 2/(e^{2x}+1). e^{2x} via single v_exp_f32; the divide via
// v_rcp_f32 (1-ulp) instead of the IEEE div sequence (~10 instrs) hipcc emits
// without -ffast-math. This is the hot op (205M tanh/iteration).
__device__ __forceinline__ float fast_tanh(float x) {
#if __has_builtin(__builtin_amdgcn_exp2f)
  const float t = __builtin_amdgcn_exp2f(x * 2.8853900817779268f);
#else
  const float t = __expf(2.f * x);
#endif
#if __has_builtin(__builtin_amdgcn_rcpf)
  return 1.f - 2.f * __builtin_amdgcn_rcpf(t + 1.f);
#else
  return 1.f - 2.f / (t + 1.f);
#endif
}

// proj[N][128] = x[N][128] @ W[128][128], 64x64 tiles -> 69.6KB LDS
// -> 2 blocks/CU (8 waves/CU); plus fused edge-histogram tail.
__global__ __launch_bounds__(256) void gemm_xW(const float* __restrict__ x,
                                               const float* __restrict__ W,
                                               float* __restrict__ proj, int N,
                                               const int* __restrict__ ecol,
                                               int* __restrict__ hist, int E) {
  __shared__ float xs[128][68];  // [k][r]
  __shared__ float ws[128][68];  // [k][c]
  const int tid = threadIdx.x;
  const int rowblk = blockIdx.x >> 1;
  const int colblk = blockIdx.x & 1;
  const int row0 = rowblk * 64;
  const int col0 = colblk * 64;

  {
    const int k = tid >> 1;
    const int c0 = (tid & 1) * 32;
    const float4* src = (const float4*)(W + (size_t)k * HC + col0 + c0);
#pragma unroll
    for (int i = 0; i < 8; ++i) *(float4*)&ws[k][c0 + i * 4] = src[i];
  }
  {
    const int r = tid >> 2;
    const int k0 = (tid & 3) * 32;
    const int grow = row0 + r;
    const bool valid = grow < N;
    const float4* src = (const float4*)(x + (size_t)grow * IN_CH + k0);
#pragma unroll
    for (int i = 0; i < 8; ++i) {
      float4 v = valid ? src[i] : make_float4(0.f, 0.f, 0.f, 0.f);
      const int k = k0 + i * 4;
      xs[k][r] = v.x; xs[k + 1][r] = v.y; xs[k + 2][r] = v.z; xs[k + 3][r] = v.w;
    }
  }
  __syncthreads();

  const int cg2 = tid & 15;
  const int rg = tid >> 4;
  float acc[4][4];
#pragma unroll
  for (int r = 0; r < 4; ++r)
#pragma unroll
    for (int c = 0; c < 4; ++c) acc[r][c] = 0.f;

#pragma unroll 8
  for (int k = 0; k < 128; ++k) {
    const float4 a = *(const float4*)&xs[k][rg * 4];
    const float4 b = *(const float4*)&ws[k][cg2 * 4];
    const float xv[4] = {a.x, a.y, a.z, a.w};
    const float wv[4] = {b.x, b.y, b.z, b.w};
#pragma unroll
    for (int r = 0; r < 4; ++r)
#pragma unroll
      for (int c = 0; c < 4; ++c) acc[r][c] += xv[r] * wv[c];
  }

#pragma unroll
  for (int r = 0; r < 4; ++r) {
    const int grow = row0 + rg * 4 + r;
    if (grow < N) {
      *(float4*)(proj + (size_t)grow * HC + col0 + cg2 * 4) =
          make_float4(acc[r][0], acc[r][1], acc[r][2], acc[r][3]);
    }
  }

  if (hist) {
    const int ehb = (E + gridDim.x - 1) / gridDim.x;
    const int estart = blockIdx.x * ehb;
    const int eend = min(estart + ehb, E);
    for (int e = estart + tid; e < eend; e += 256) atomicAdd(&hist[ecol[e]], 1);
  }
}

__device__ __forceinline__ int block_scan_excl(int tsum, int* ls, int tid, int* total) {
  ls[tid] = tsum;
  __syncthreads();
  for (int off = 1; off < 256; off <<= 1) {
    int v = (tid >= off) ? ls[tid - off] : 0;
    __syncthreads();
    ls[tid] += v;
    __syncthreads();
  }
  *total = ls[255];
  return ls[tid] - tsum;
}

// Single-pass scan: each chunk-block scans its 2048 counters, publishes its
// total (release flag, agent scope), then sums predecessors' totals after
// acquiring their flags. nc<=256 blocks are always co-resident -> no deadlock.
// No grid.sync (round-7 lesson: coop sync is catastrophically slow here).
__global__ __launch_bounds__(256) void k_scan(const int* __restrict__ hist,
                                              int* __restrict__ sums,
                                              unsigned* __restrict__ flags,
                                              int* __restrict__ starts,
                                              int* __restrict__ cursor,
                                              int nb, int nc) {
  __shared__ int ls[256];
  const int tid = threadIdx.x;
  const int bid = blockIdx.x;
  const int base = bid * CHUNK + tid * 8;
  int h[8];
  int t = 0;
#pragma unroll
  for (int j = 0; j < 8; ++j) {
    const int i = base + j;
    h[j] = (i < nb) ? hist[i] : 0;
    t += h[j];
  }
  int total;
  const int excl = block_scan_excl(t, ls, tid, &total);
  if (tid == 0) {
    __hip_atomic_store(&sums[bid], total, __ATOMIC_RELAXED, __HIP_MEMORY_SCOPE_AGENT);
    __hip_atomic_store(&flags[bid], 1u, __ATOMIC_RELEASE, __HIP_MEMORY_SCOPE_AGENT);
  }
  int my = 0;
  if (tid < bid) {
    while (__hip_atomic_load(&flags[tid], __ATOMIC_ACQUIRE, __HIP_MEMORY_SCOPE_AGENT) == 0u) {}
    my = __hip_atomic_load(&sums[tid], __ATOMIC_RELAXED, __HIP_MEMORY_SCOPE_AGENT);
  }
  __syncthreads();  // all spins done; ls free for reuse
  ls[tid] = my;
  __syncthreads();
  for (int off = 128; off >= 1; off >>= 1) {
    if (tid < off) ls[tid] += ls[tid + off];
    __syncthreads();
  }
  const int cbase = ls[0];
  int run = cbase + excl;
#pragma unroll
  for (int j = 0; j < 8; ++j) {
    const int i = base + j;
    if (i < nb) { starts[i] = run; cursor[i] = run; run += h[j]; }
  }
  if (bid == nc - 1 && tid == 0) {
    starts[nb] = cbase + total;
    cursor[nb] = cbase + total;
  }
}

// CSR permutation: rc[p] = src row * HC (pre-scaled float offset), grouped by dst.
__global__ __launch_bounds__(256) void scatter_rc(const int* __restrict__ erow,
                                                  const int* __restrict__ ecol,
                                                  int* __restrict__ cursor,
                                                  int* __restrict__ rc, int E) {
  const int i = blockIdx.x * 256 + threadIdx.x;
  if (i < E) {
    const int p = atomicAdd(&cursor[ecol[i]], 1);
    rc[p] = erow[i] * HC;
  }
}

// Wave per dst node, HALF-WAVE per edge, 8-edge main unroll: lane l (0..31)
// owns float4 of channels 4l..4l+3 (head = l>>3). rc holds pre-scaled row*HC so
// each gather address is a single add. Stabilizer = analytic bound
// M0_h = sum|att[h]| (cancels in the ratio); true per-head max tracked so
// fix_clamp reproduces max(norm,1e-12) exactly.
__global__ __launch_bounds__(256) void fused_apply(const float* __restrict__ proj,
                                                   const int* __restrict__ rc,
                                                   const int* __restrict__ starts,
                                                   const float* __restrict__ att,
                                                   float* __restrict__ out,
                                                   float* __restrict__ den,
                                                   unsigned* __restrict__ headmax_u, int N) {
  __shared__ unsigned blkmax[HEADS];
  const int tid = threadIdx.x;
  if (tid < HEADS) blkmax[tid] = 0u;
  __syncthreads();
  const int lane = tid & 63;
  const int half = lane >> 5;
  const int l = lane & 31;
  const int c0 = l * 4;
  const int head = l >> 3;
  const int n = blockIdx.x * 4 + (tid >> 6);
  float lm = -3.0e38f;

  if (n < N) {
    const float4 a4 = ((const float4*)att)[l];
    float M0 = fabsf(a4.x) + fabsf(a4.y) + fabsf(a4.z) + fabsf(a4.w);
    M0 += __shfl_xor(M0, 4, 64);
    M0 += __shfl_xor(M0, 2, 64);
    M0 += __shfl_xor(M0, 1, 64);
    const float4 d4 = *(const float4*)(proj + (size_t)n * HC + c0);
    const int beg = __builtin_amdgcn_readfirstlane(starts[n]);
    const int end = __builtin_amdgcn_readfirstlane(starts[n + 1]);

    float ax = 0.f, ay = 0.f, az = 0.f, aw = 0.f, dsum = 0.f;
    int i = beg;
    // main: 8 edges/iteration (4 per half-wave) -> 4 gathers in flight/lane
    for (; i + 8 <= end; i += 8) {
      const int r0 = rc[i + half];
      const int r1 = rc[i + 2 + half];
      const int r2 = rc[i + 4 + half];
      const int r3 = rc[i + 6 + half];
      const float4 s0 = *(const float4*)(proj + r0 + c0);
      const float4 s1 = *(const float4*)(proj + r1 + c0);
      const float4 s2 = *(const float4*)(proj + r2 + c0);
      const float4 s3 = *(const float4*)(proj + r3 + c0);
      float p0 = fast_tanh(s0.x + d4.x) * a4.x + fast_tanh(s0.y + d4.y) * a4.y
               + fast_tanh(s0.z + d4.z) * a4.z + fast_tanh(s0.w + d4.w) * a4.w;
      float p1 = fast_tanh(s1.x + d4.x) * a4.x + fast_tanh(s1.y + d4.y) * a4.y
               + fast_tanh(s1.z + d4.z) * a4.z + fast_tanh(s1.w + d4.w) * a4.w;
      float p2 = fast_tanh(s2.x + d4.x) * a4.x + fast_tanh(s2.y + d4.y) * a4.y
               + fast_tanh(s2.z + d4.z) * a4.z + fast_tanh(s2.w + d4.w) * a4.w;
      float p3 = fast_tanh(s3.x + d4.x) * a4.x + fast_tanh(s3.y + d4.y) * a4.y
               + fast_tanh(s3.z + d4.z) * a4.z + fast_tanh(s3.w + d4.w) * a4.w;
      p0 += __shfl_xor(p0, 4, 64);  p1 += __shfl_xor(p1, 4, 64);
      p2 += __shfl_xor(p2, 4, 64);  p3 += __shfl_xor(p3, 4, 64);
      p0 += __shfl_xor(p0, 2, 64);  p1 += __shfl_xor(p1, 2, 64);
      p2 += __shfl_xor(p2, 2, 64);  p3 += __shfl_xor(p3, 2, 64);
      p0 += __shfl_xor(p0, 1, 64);  p1 += __shfl_xor(p1, 1, 64);
      p2 += __shfl_xor(p2, 1, 64);  p3 += __shfl_xor(p3, 1, 64);
      lm = fmaxf(lm, fmaxf(fmaxf(p0, p1), fmaxf(p2, p3)));
      const float e0 = __expf(p0 - M0);
      const float e1 = __expf(p1 - M0);
      const float e2 = __expf(p2 - M0);
      const float e3 = __expf(p3 - M0);
      ax += s0.x * e0 + s1.x * e1 + s2.x * e2 + s3.x * e3;
      ay += s0.y * e0 + s1.y * e1 + s2.y * e2 + s3.y * e3;
      az += s0.z * e0 + s1.z * e1 + s2.z * e2 + s3.z * e3;
      aw += s0.w * e0 + s1.w * e1 + s2.w * e2 + s3.w * e3;
      dsum += (e0 + e1) + (e2 + e3);
    }
    // middle: one 4-edge step
    if (i + 4 <= end) {
      const int r0 = rc[i + half];
      const int r1 = rc[i + 2 + half];
      const float4 s0 = *(const float4*)(proj + r0 + c0);
      const float4 s1 = *(const float4*)(proj + r1 + c0);
      float p0 = fast_tanh(s0.x + d4.x) * a4.x + fast_tanh(s0.y + d4.y) * a4.y
               + fast_tanh(s0.z + d4.z) * a4.z + fast_tanh(s0.w + d4.w) * a4.w;
      float p1 = fast_tanh(s1.x + d4.x) * a4.x + fast_tanh(s1.y + d4.y) * a4.y
               + fast_tanh(s1.z + d4.z) * a4.z + fast_tanh(s1.w + d4.w) * a4.w;
      p0 += __shfl_xor(p0, 4, 64);  p1 += __shfl_xor(p1, 4, 64);
      p0 += __shfl_xor(p0, 2, 64);  p1 += __shfl_xor(p1, 2, 64);
      p0 += __shfl_xor(p0, 1, 64);  p1 += __shfl_xor(p1, 1, 64);
      lm = fmaxf(lm, fmaxf(p0, p1));
      const float e0 = __expf(p0 - M0);
      const float e1 = __expf(p1 - M0);
      ax += s0.x * e0 + s1.x * e1;
      ay += s0.y * e0 + s1.y * e1;
      az += s0.z * e0 + s1.z * e1;
      aw += s0.w * e0 + s1.w * e1;
      dsum += e0 + e1;
      i += 4;
    }
    // tail: 2 edges/iteration, masked
    for (; i < end; i += 2) {
      const int idx = i + half;
      const bool valid = idx < end;
      const int row = rc[valid ? idx : i];
      const float4 s4 = *(const float4*)(proj + row + c0);
      float p = fast_tanh(s4.x + d4.x) * a4.x
              + fast_tanh(s4.y + d4.y) * a4.y
              + fast_tanh(s4.z + d4.z) * a4.z
              + fast_tanh(s4.w + d4.w) * a4.w;
      p += __shfl_xor(p, 4, 64);
      p += __shfl_xor(p, 2, 64);
      p += __shfl_xor(p, 1, 64);
      if (!valid) p = -3.0e38f;
      lm = fmaxf(lm, p);
      const float e = __expf(p - M0);
      ax += s4.x * e; ay += s4.y * e; az += s4.z * e; aw += s4.w * e;
      dsum += e;
    }
    // merge halves
    dsum += __shfl_xor(dsum, 32, 64);
    ax += __shfl_xor(ax, 32, 64);
    ay += __shfl_xor(ay, 32, 64);
    az += __shfl_xor(az, 32, 64);
    aw += __shfl_xor(aw, 32, 64);
    lm = fmaxf(lm, __shfl_xor(lm, 32, 64));
    if (half == 0) {
      const float inv = 1.f / fmaxf(dsum, 1e-38f);
      *(float4*)(out + (size_t)n * HC + c0) =
          make_float4(ax * inv, ay * inv, az * inv, aw * inv);
      if ((l & 7) == 0) den[n * HEADS + head] = dsum;
      if ((l & 7) == 0) atomicMax(&blkmax[head], flip_f32(lm));
    }
  }
  __syncthreads();
  if (tid < HEADS) {
    const unsigned v = blkmax[tid];
    if (v > headmax_u[tid]) atomicMax(&headmax_u[tid], v);
  }
}

// Reference normalizer = den * exp(M0_h - Mt_h). If below 1e-12 the reference
// clamps: out_ref = out_ours * (ref_den / 1e-12). Apply that correction.
__global__ __launch_bounds__(256) void fix_clamp(float* __restrict__ out,
                                                 const float* __restrict__ den,
                                                 const unsigned* __restrict__ headmax_u,
                                                 const float* __restrict__ att, int N) {
  const int t = blockIdx.x * 256 + threadIdx.x;
  if (t >= N * HEADS) return;
  const int n = t >> 2;
  const int h = t & 3;
  float M0 = 0.f;
#pragma unroll
  for (int c = 0; c < OUT_CH; ++c) M0 += fabsf(att[h * OUT_CH + c]);
  const float Mt = unflip_f32(headmax_u[h]);
  const float f = den[t] * __expf(M0 - Mt);
  if (f < 1e-12f) {
    const float s = f * 1e12f;
    float4* p = (float4*)(out + (size_t)n * HC + h * OUT_CH);
#pragma unroll
    for (int j = 0; j < 8; ++j) {
      float4 v = p[j];
      v.x *= s; v.y *= s; v.z *= s; v.w *= s;
      p[j] = v;
    }
  }
}

// blockmax -> corr (fallback path only)
__global__ __launch_bounds__(256) void reduce_corr(const unsigned* __restrict__ blockmax,
                                                   const float* __restrict__ att,
                                                   float* __restrict__ corr, int nblk) {
  __shared__ unsigned sm[HEADS];
  const int tid = threadIdx.x;
  if (tid < HEADS) sm[tid] = 0u;
  __syncthreads();
  const int h = tid & 3;
  unsigned k = 0u;
  for (int i = tid >> 2; i < nblk; i += 64) k = max(k, blockmax[i * HEADS + h]);
  atomicMax(&sm[h], k);
  __syncthreads();
  if (tid < HEADS) {
    const float Mt = unflip_f32(sm[tid]);
    float M0 = 0.f;
#pragma unroll
    for (int c = 0; c < OUT_CH; ++c) M0 += fabsf(att[tid * OUT_CH + c]);
    corr[tid] = __expf(M0 - Mt);
    corr[4 + tid] = Mt;
  }
}

// --- fallback path (ws too small): score-max pass + edge-parallel atomics ---
__global__ __launch_bounds__(256) void score_max(const float* __restrict__ proj,
                                                 const int* __restrict__ erow,
                                                 const int* __restrict__ ecol,
                                                 const float* __restrict__ att,
                                                 unsigned* __restrict__ blockmax, int E) {
  __shared__ unsigned blkmax[HEADS];
  const int tid = threadIdx.x;
  if (tid < HEADS) blkmax[tid] = 0u;
  __syncthreads();
  const int lane = tid & 63;
  const int wid = tid >> 6;
  const float a0 = att[lane];
  const float a1 = att[lane + 64];
  float lmA = -3.0e38f, lmB = -3.0e38f;
  const int stride = SCORE_BLOCKS * 16;

  for (int base = (blockIdx.x * 4 + wid) * 4; base < E; base += stride) {
    const int bu = __builtin_amdgcn_readfirstlane(base);
    const int lim = min(bu + 4, E);
    for (int e = bu; e < lim; ++e) {
      const int r0 = erow[e], c0 = ecol[e];
      const float* ps = proj + (size_t)r0 * HC;
      const float* pd = proj + (size_t)c0 * HC;
      float pA = fast_tanh(ps[lane] + pd[lane]) * a0;
      float pB = fast_tanh(ps[lane + 64] + pd[lane + 64]) * a1;
#pragma unroll
      for (int m = 16; m >= 1; m >>= 1) {
        pA += __shfl_xor(pA, m, 64);
        pB += __shfl_xor(pB, m, 64);
      }
      lmA = fmaxf(lmA, pA);
      lmB = fmaxf(lmB, pB);
    }
  }
  if ((lane & 31) == 0) {
    const int hh = lane >> 5;
    atomicMax(&blkmax[hh], flip_f32(lmA));
    atomicMax(&blkmax[hh + 2], flip_f32(lmB));
  }
  __syncthreads();
  if (tid < HEADS) blockmax[blockIdx.x * HEADS + tid] = blkmax[tid];
}

__global__ __launch_bounds__(256) void edge_apply_fb(const float* __restrict__ proj,
                                                     const int* __restrict__ erow,
                                                     const int* __restrict__ ecol,
                                                     const float* __restrict__ att,
                                                     const float* __restrict__ headmax,
                                                     float* __restrict__ out,
                                                     float* __restrict__ norm, int E) {
  const int tid = threadIdx.x;
  const int e = blockIdx.x * 2 + (tid >> 7);
  if (e >= E) return;
  const int ch = tid & 127;
  const int h = ch >> 5;
  const float M = headmax[h];
  const int row = erow[e];
  const int col = ecol[e];
  const float sv = proj[(size_t)row * HC + ch];
  const float dv = proj[(size_t)col * HC + ch];
  float p = fast_tanh(sv + dv) * att[ch];
#pragma unroll
  for (int m = 16; m >= 1; m >>= 1) p += __shfl_xor(p, m, 64);
  const float w = __expf(p - M);
  unsafeAtomicAdd(&out[(size_t)col * HC + ch], sv * w);
  if ((ch & 31) == 0) unsafeAtomicAdd(&norm[(size_t)col * HEADS + h], w);
}

__global__ __launch_bounds__(256) void finalize_fb(float* __restrict__ out,
                                                   const float* __restrict__ norm, int N) {
  const int idx = blockIdx.x * blockDim.x + threadIdx.x;
  const int total = N * (HC / 4);
  if (idx >= total) return;
  const int base = idx * 4;
  const int node = base >> 7;
  const int h = (base >> 5) & 3;
  const float inv = 1.f / fmaxf(norm[node * HEADS + h], 1e-12f);
  float4 v = ((float4*)out)[idx];
  v.x *= inv; v.y *= inv; v.z *= inv; v.w *= inv;
  ((float4*)out)[idx] = v;
}

extern "C" void kernel_launch(void* const* d_in, const int* in_sizes, int n_in,
                              void* d_out, int out_size, void* d_ws, size_t ws_size,
                              hipStream_t stream) {
  const float* x    = (const float*)d_in[0];
  const int*   eidx = (const int*)d_in[1];  // [2][E]: row(src) then col(dst)
  const float* W    = (const float*)d_in[2];
  const float* att  = (const float*)d_in[3];
  float* out = (float*)d_out;

  const int N = in_sizes[0] / IN_CH;
  const int E = in_sizes[1] / 2;
  const int nb = N;
  const int nc = (nb + CHUNK - 1) / CHUNK;  // scan chunks (<=256 supported)
  const int ngemm = ((N + 63) / 64) * 2;    // 64-row x 64-col tiles

  // ws layout (16B-aligned pieces)
  char* p = (char*)d_ws;
  float* proj = (float*)p;  p += (size_t)N * HC * 4;
  int* rc = (int*)p;        p += (((size_t)E * 4 + 15) & ~15ull);
  float* den = (float*)p;   p += (((size_t)N * HEADS * 4 + 15) & ~15ull);
  int* hist = (int*)p;      p += (((size_t)(nb + 4 + 256) * 4 + 15) & ~15ull);  // + headmax_u + flags
  int* starts = (int*)p;    p += (((size_t)(nb + 1) * 4 + 15) & ~15ull);
  int* cursor = (int*)p;    p += (((size_t)(nb + 1) * 4 + 15) & ~15ull);
  int* sums = (int*)p;      p += 1024;
  unsigned* headmax_u = (unsigned*)(hist + nb);
  unsigned* flags = (unsigned*)(hist + nb + 4);
  const size_t need_full = (size_t)(p - (char*)d_ws);
  const bool full = (ws_size >= need_full) && (nc <= 256);

  if (full) {
    hipMemsetAsync(hist, 0, (size_t)(nb + 4 + 256) * sizeof(int), stream);  // hist+headmax+flags
    gemm_xW<<<ngemm, 256, 0, stream>>>(x, W, proj, N, eidx + E, hist, E);
    k_scan<<<nc, 256, 0, stream>>>(hist, sums, flags, starts, cursor, nb, nc);
    scatter_rc<<<(E + 255) / 256, 256, 0, stream>>>(eidx, eidx + E, cursor, rc, E);
    fused_apply<<<(N + 3) / 4, 256, 0, stream>>>(proj, rc, starts, att, out, den,
                                                 headmax_u, N);
    fix_clamp<<<(N * HEADS + 255) / 256, 256, 0, stream>>>(out, den, headmax_u, att, N);
  } else {
    // minimal-ws fallback: blockmax/corr/norm packed right after proj
    gemm_xW<<<ngemm, 256, 0, stream>>>(x, W, proj, N, nullptr, nullptr, 0);
    unsigned* bm = (unsigned*)(proj + (size_t)N * HC);
    float* cr = (float*)(bm + SCORE_BLOCKS * HEADS);
    float* norm = cr + 8;
    hipMemsetAsync(out, 0, (size_t)out_size * sizeof(float), stream);
    hipMemsetAsync(norm, 0, (size_t)N * HEADS * sizeof(float), stream);
    score_max<<<SCORE_BLOCKS, 256, 0, stream>>>(proj, eidx, eidx + E, att, bm, E);
    reduce_corr<<<1, 256, 0, stream>>>(bm, att, cr, SCORE_BLOCKS);
    edge_apply_fb<<<(E + 1) / 2, 256, 0, stream>>>(proj, eidx, eidx + E, att, cr + 4, out, norm, E);
    finalize_fb<<<(N * (HC / 4) + 255) / 256, 256, 0, stream>>>(out, norm, N);
  }
}

// Round 9
// 425.244 us; speedup vs baseline: 2.2949x; 1.0675x over previous
//
#include <hip/hip_runtime.h>

#define IN_CH 128
#define HEADS 4
#define OUT_CH 32
#define HC 128           // HEADS*OUT_CH
#define SCORE_BLOCKS 4096
#define CHUNK 2048       // scan chunk (256 thr x 8)
#define BW_SHIFT 9       // bucket = 512 nodes
#define BW (1 << BW_SHIFT)

__device__ __forceinline__ unsigned flip_f32(float x) {
  unsigned u = __float_as_uint(x);
  return (u & 0x80000000u) ? ~u : (u | 0x80000000u);
}
__device__ __forceinline__ float unflip_f32(unsigned k) {
  unsigned u = (k & 0x80000000u) ? (k ^ 0x80000000u) : ~k;
  return __uint_as_float(u);
}
// tanh(x) = 1 - 2/(e^{2x}+1): single v_exp_f32 + v_rcp_f32 (1-ulp).
__device__ __forceinline__ float fast_tanh(float x) {
#if __has_builtin(__builtin_amdgcn_exp2f)
  const float t = __builtin_amdgcn_exp2f(x * 2.8853900817779268f);
#else
  const float t = __expf(2.f * x);
#endif
#if __has_builtin(__builtin_amdgcn_rcpf)
  return 1.f - 2.f * __builtin_amdgcn_rcpf(t + 1.f);
#else
  return 1.f - 2.f / (t + 1.f);
#endif
}

// proj[N][128] = x[N][128] @ W[128][128], 64x64 tiles -> 69.6KB LDS
// -> 2 blocks/CU (8 waves/CU); plus fused edge-histogram tail.
__global__ __launch_bounds__(256) void gemm_xW(const float* __restrict__ x,
                                               const float* __restrict__ W,
                                               float* __restrict__ proj, int N,
                                               const int* __restrict__ ecol,
                                               int* __restrict__ hist, int E) {
  __shared__ float xs[128][68];  // [k][r]
  __shared__ float ws[128][68];  // [k][c]
  const int tid = threadIdx.x;
  const int rowblk = blockIdx.x >> 1;
  const int colblk = blockIdx.x & 1;
  const int row0 = rowblk * 64;
  const int col0 = colblk * 64;

  {
    const int k = tid >> 1;
    const int c0 = (tid & 1) * 32;
    const float4* src = (const float4*)(W + (size_t)k * HC + col0 + c0);
#pragma unroll
    for (int i = 0; i < 8; ++i) *(float4*)&ws[k][c0 + i * 4] = src[i];
  }
  {
    const int r = tid >> 2;
    const int k0 = (tid & 3) * 32;
    const int grow = row0 + r;
    const bool valid = grow < N;
    const float4* src = (const float4*)(x + (size_t)grow * IN_CH + k0);
#pragma unroll
    for (int i = 0; i < 8; ++i) {
      float4 v = valid ? src[i] : make_float4(0.f, 0.f, 0.f, 0.f);
      const int k = k0 + i * 4;
      xs[k][r] = v.x; xs[k + 1][r] = v.y; xs[k + 2][r] = v.z; xs[k + 3][r] = v.w;
    }
  }
  __syncthreads();

  const int cg2 = tid & 15;
  const int rg = tid >> 4;
  float acc[4][4];
#pragma unroll
  for (int r = 0; r < 4; ++r)
#pragma unroll
    for (int c = 0; c < 4; ++c) acc[r][c] = 0.f;

#pragma unroll 8
  for (int k = 0; k < 128; ++k) {
    const float4 a = *(const float4*)&xs[k][rg * 4];
    const float4 b = *(const float4*)&ws[k][cg2 * 4];
    const float xv[4] = {a.x, a.y, a.z, a.w};
    const float wv[4] = {b.x, b.y, b.z, b.w};
#pragma unroll
    for (int r = 0; r < 4; ++r)
#pragma unroll
      for (int c = 0; c < 4; ++c) acc[r][c] += xv[r] * wv[c];
  }

#pragma unroll
  for (int r = 0; r < 4; ++r) {
    const int grow = row0 + rg * 4 + r;
    if (grow < N) {
      *(float4*)(proj + (size_t)grow * HC + col0 + cg2 * 4) =
          make_float4(acc[r][0], acc[r][1], acc[r][2], acc[r][3]);
    }
  }

  if (hist) {
    const int ehb = (E + gridDim.x - 1) / gridDim.x;
    const int estart = blockIdx.x * ehb;
    const int eend = min(estart + ehb, E);
    for (int e = estart + tid; e < eend; e += 256) atomicAdd(&hist[ecol[e]], 1);
  }
}

__device__ __forceinline__ int block_scan_excl(int tsum, int* ls, int tid, int* total) {
  ls[tid] = tsum;
  __syncthreads();
  for (int off = 1; off < 256; off <<= 1) {
    int v = (tid >= off) ? ls[tid - off] : 0;
    __syncthreads();
    ls[tid] += v;
    __syncthreads();
  }
  *total = ls[255];
  return ls[tid] - tsum;
}

// Single-pass scan with release/acquire flag handshake (no coop grid.sync).
__global__ __launch_bounds__(256) void k_scan(const int* __restrict__ hist,
                                              int* __restrict__ sums,
                                              unsigned* __restrict__ flags,
                                              int* __restrict__ starts,
                                              int nb, int nc) {
  __shared__ int ls[256];
  const int tid = threadIdx.x;
  const int bid = blockIdx.x;
  const int base = bid * CHUNK + tid * 8;
  int h[8];
  int t = 0;
#pragma unroll
  for (int j = 0; j < 8; ++j) {
    const int i = base + j;
    h[j] = (i < nb) ? hist[i] : 0;
    t += h[j];
  }
  int total;
  const int excl = block_scan_excl(t, ls, tid, &total);
  if (tid == 0) {
    __hip_atomic_store(&sums[bid], total, __ATOMIC_RELAXED, __HIP_MEMORY_SCOPE_AGENT);
    __hip_atomic_store(&flags[bid], 1u, __ATOMIC_RELEASE, __HIP_MEMORY_SCOPE_AGENT);
  }
  int my = 0;
  if (tid < bid) {
    while (__hip_atomic_load(&flags[tid], __ATOMIC_ACQUIRE, __HIP_MEMORY_SCOPE_AGENT) == 0u) {}
    my = __hip_atomic_load(&sums[tid], __ATOMIC_RELAXED, __HIP_MEMORY_SCOPE_AGENT);
  }
  __syncthreads();  // all spins done; ls free for reuse
  ls[tid] = my;
  __syncthreads();
  for (int off = 128; off >= 1; off >>= 1) {
    if (tid < off) ls[tid] += ls[tid + off];
    __syncthreads();
  }
  const int cbase = ls[0];
  int run = cbase + excl;
#pragma unroll
  for (int j = 0; j < 8; ++j) {
    const int i = base + j;
    if (i < nb) { starts[i] = run; run += h[j]; }
  }
  if (bid == nc - 1 && tid == 0) starts[nb] = cbase + total;
}

// Phase A: LDS multisplit of edges into per-bucket aux regions (bucket = 512
// consecutive dst nodes; region = [starts[b*512], starts[(b+1)*512]) -- exact
// size, no overflow possible). Per-block contiguous runs kill the 8x write
// amplification of the old global random scatter.
__global__ __launch_bounds__(256) void bucket_split(const int* __restrict__ erow,
                                                    const int* __restrict__ ecol,
                                                    const int* __restrict__ starts,
                                                    int* __restrict__ bcnt,
                                                    int2* __restrict__ aux,
                                                    int E, int NB) {
  __shared__ int cnt[1024];
  __shared__ int base[1024];
  const int tid = threadIdx.x;
  for (int b = tid; b < NB; b += 256) cnt[b] = 0;
  __syncthreads();
  const int e0 = blockIdx.x * 2048;
  int rows[8], cols[8], loc[8];
#pragma unroll
  for (int j = 0; j < 8; ++j) {
    const int e = e0 + j * 256 + tid;
    if (e < E) {
      cols[j] = ecol[e];
      rows[j] = erow[e];
      loc[j] = atomicAdd(&cnt[cols[j] >> BW_SHIFT], 1);
    } else {
      loc[j] = -1;
    }
  }
  __syncthreads();
  for (int b = tid; b < NB; b += 256) {
    const int c = cnt[b];
    base[b] = (c ? atomicAdd(&bcnt[b], c) : 0) + starts[b << BW_SHIFT];
  }
  __syncthreads();
#pragma unroll
  for (int j = 0; j < 8; ++j) {
    if (loc[j] >= 0) {
      const int b = cols[j] >> BW_SHIFT;
      aux[base[b] + loc[j]] = make_int2(rows[j] * HC, cols[j]);
    }
  }
}

// Phase B: one block per bucket; LDS per-node rank counters; rc writes land in
// one contiguous ~32KB region (single-XCD L2 resident). No global atomics.
__global__ __launch_bounds__(256) void bucket_place(const int2* __restrict__ aux,
                                                    const int* __restrict__ starts,
                                                    int* __restrict__ rc, int N) {
  __shared__ int lcnt[BW];
  const int tid = threadIdx.x;
  const int n0 = blockIdx.x << BW_SHIFT;
  const int n1 = min(n0 + BW, N);
  for (int i = tid; i < BW; i += 256) lcnt[i] = 0;
  __syncthreads();
  const int e0 = starts[n0];
  const int e1 = starts[n1];
  for (int i = e0 + tid; i < e1; i += 256) {
    const int2 pr = aux[i];
    const int r = atomicAdd(&lcnt[pr.y & (BW - 1)], 1);
    rc[starts[pr.y] + r] = pr.x;
  }
}

// Wave per dst node, HALF-WAVE per edge, 8-edge main unroll (round-8 verified).
__global__ __launch_bounds__(256) void fused_apply(const float* __restrict__ proj,
                                                   const int* __restrict__ rc,
                                                   const int* __restrict__ starts,
                                                   const float* __restrict__ att,
                                                   float* __restrict__ out,
                                                   float* __restrict__ den,
                                                   unsigned* __restrict__ headmax_u, int N) {
  __shared__ unsigned blkmax[HEADS];
  const int tid = threadIdx.x;
  if (tid < HEADS) blkmax[tid] = 0u;
  __syncthreads();
  const int lane = tid & 63;
  const int half = lane >> 5;
  const int l = lane & 31;
  const int c0 = l * 4;
  const int head = l >> 3;
  const int n = blockIdx.x * 4 + (tid >> 6);
  float lm = -3.0e38f;

  if (n < N) {
    const float4 a4 = ((const float4*)att)[l];
    float M0 = fabsf(a4.x) + fabsf(a4.y) + fabsf(a4.z) + fabsf(a4.w);
    M0 += __shfl_xor(M0, 4, 64);
    M0 += __shfl_xor(M0, 2, 64);
    M0 += __shfl_xor(M0, 1, 64);
    const float4 d4 = *(const float4*)(proj + (size_t)n * HC + c0);
    const int beg = __builtin_amdgcn_readfirstlane(starts[n]);
    const int end = __builtin_amdgcn_readfirstlane(starts[n + 1]);

    float ax = 0.f, ay = 0.f, az = 0.f, aw = 0.f, dsum = 0.f;
    int i = beg;
    for (; i + 8 <= end; i += 8) {
      const int r0 = rc[i + half];
      const int r1 = rc[i + 2 + half];
      const int r2 = rc[i + 4 + half];
      const int r3 = rc[i + 6 + half];
      const float4 s0 = *(const float4*)(proj + r0 + c0);
      const float4 s1 = *(const float4*)(proj + r1 + c0);
      const float4 s2 = *(const float4*)(proj + r2 + c0);
      const float4 s3 = *(const float4*)(proj + r3 + c0);
      float p0 = fast_tanh(s0.x + d4.x) * a4.x + fast_tanh(s0.y + d4.y) * a4.y
               + fast_tanh(s0.z + d4.z) * a4.z + fast_tanh(s0.w + d4.w) * a4.w;
      float p1 = fast_tanh(s1.x + d4.x) * a4.x + fast_tanh(s1.y + d4.y) * a4.y
               + fast_tanh(s1.z + d4.z) * a4.z + fast_tanh(s1.w + d4.w) * a4.w;
      float p2 = fast_tanh(s2.x + d4.x) * a4.x + fast_tanh(s2.y + d4.y) * a4.y
               + fast_tanh(s2.z + d4.z) * a4.z + fast_tanh(s2.w + d4.w) * a4.w;
      float p3 = fast_tanh(s3.x + d4.x) * a4.x + fast_tanh(s3.y + d4.y) * a4.y
               + fast_tanh(s3.z + d4.z) * a4.z + fast_tanh(s3.w + d4.w) * a4.w;
      p0 += __shfl_xor(p0, 4, 64);  p1 += __shfl_xor(p1, 4, 64);
      p2 += __shfl_xor(p2, 4, 64);  p3 += __shfl_xor(p3, 4, 64);
      p0 += __shfl_xor(p0, 2, 64);  p1 += __shfl_xor(p1, 2, 64);
      p2 += __shfl_xor(p2, 2, 64);  p3 += __shfl_xor(p3, 2, 64);
      p0 += __shfl_xor(p0, 1, 64);  p1 += __shfl_xor(p1, 1, 64);
      p2 += __shfl_xor(p2, 1, 64);  p3 += __shfl_xor(p3, 1, 64);
      lm = fmaxf(lm, fmaxf(fmaxf(p0, p1), fmaxf(p2, p3)));
      const float e0 = __expf(p0 - M0);
      const float e1 = __expf(p1 - M0);
      const float e2 = __expf(p2 - M0);
      const float e3 = __expf(p3 - M0);
      ax += s0.x * e0 + s1.x * e1 + s2.x * e2 + s3.x * e3;
      ay += s0.y * e0 + s1.y * e1 + s2.y * e2 + s3.y * e3;
      az += s0.z * e0 + s1.z * e1 + s2.z * e2 + s3.z * e3;
      aw += s0.w * e0 + s1.w * e1 + s2.w * e2 + s3.w * e3;
      dsum += (e0 + e1) + (e2 + e3);
    }
    if (i + 4 <= end) {
      const int r0 = rc[i + half];
      const int r1 = rc[i + 2 + half];
      const float4 s0 = *(const float4*)(proj + r0 + c0);
      const float4 s1 = *(const float4*)(proj + r1 + c0);
      float p0 = fast_tanh(s0.x + d4.x) * a4.x + fast_tanh(s0.y + d4.y) * a4.y
               + fast_tanh(s0.z + d4.z) * a4.z + fast_tanh(s0.w + d4.w) * a4.w;
      float p1 = fast_tanh(s1.x + d4.x) * a4.x + fast_tanh(s1.y + d4.y) * a4.y
               + fast_tanh(s1.z + d4.z) * a4.z + fast_tanh(s1.w + d4.w) * a4.w;
      p0 += __shfl_xor(p0, 4, 64);  p1 += __shfl_xor(p1, 4, 64);
      p0 += __shfl_xor(p0, 2, 64);  p1 += __shfl_xor(p1, 2, 64);
      p0 += __shfl_xor(p0, 1, 64);  p1 += __shfl_xor(p1, 1, 64);
      lm = fmaxf(lm, fmaxf(p0, p1));
      const float e0 = __expf(p0 - M0);
      const float e1 = __expf(p1 - M0);
      ax += s0.x * e0 + s1.x * e1;
      ay += s0.y * e0 + s1.y * e1;
      az += s0.z * e0 + s1.z * e1;
      aw += s0.w * e0 + s1.w * e1;
      dsum += e0 + e1;
      i += 4;
    }
    for (; i < end; i += 2) {
      const int idx = i + half;
      const bool valid = idx < end;
      const int row = rc[valid ? idx : i];
      const float4 s4 = *(const float4*)(proj + row + c0);
      float p = fast_tanh(s4.x + d4.x) * a4.x
              + fast_tanh(s4.y + d4.y) * a4.y
              + fast_tanh(s4.z + d4.z) * a4.z
              + fast_tanh(s4.w + d4.w) * a4.w;
      p += __shfl_xor(p, 4, 64);
      p += __shfl_xor(p, 2, 64);
      p += __shfl_xor(p, 1, 64);
      if (!valid) p = -3.0e38f;
      lm = fmaxf(lm, p);
      const float e = __expf(p - M0);
      ax += s4.x * e; ay += s4.y * e; az += s4.z * e; aw += s4.w * e;
      dsum += e;
    }
    dsum += __shfl_xor(dsum, 32, 64);
    ax += __shfl_xor(ax, 32, 64);
    ay += __shfl_xor(ay, 32, 64);
    az += __shfl_xor(az, 32, 64);
    aw += __shfl_xor(aw, 32, 64);
    lm = fmaxf(lm, __shfl_xor(lm, 32, 64));
    if (half == 0) {
      const float inv = 1.f / fmaxf(dsum, 1e-38f);
      *(float4*)(out + (size_t)n * HC + c0) =
          make_float4(ax * inv, ay * inv, az * inv, aw * inv);
      if ((l & 7) == 0) den[n * HEADS + head] = dsum;
      if ((l & 7) == 0) atomicMax(&blkmax[head], flip_f32(lm));
    }
  }
  __syncthreads();
  if (tid < HEADS) {
    const unsigned v = blkmax[tid];
    if (v > headmax_u[tid]) atomicMax(&headmax_u[tid], v);
  }
}

// Reference normalizer = den * exp(M0_h - Mt_h). If below 1e-12 the reference
// clamps: out_ref = out_ours * (ref_den / 1e-12).
__global__ __launch_bounds__(256) void fix_clamp(float* __restrict__ out,
                                                 const float* __restrict__ den,
                                                 const unsigned* __restrict__ headmax_u,
                                                 const float* __restrict__ att, int N) {
  const int t = blockIdx.x * 256 + threadIdx.x;
  if (t >= N * HEADS) return;
  const int n = t >> 2;
  const int h = t & 3;
  float M0 = 0.f;
#pragma unroll
  for (int c = 0; c < OUT_CH; ++c) M0 += fabsf(att[h * OUT_CH + c]);
  const float Mt = unflip_f32(headmax_u[h]);
  const float f = den[t] * __expf(M0 - Mt);
  if (f < 1e-12f) {
    const float s = f * 1e12f;
    float4* p = (float4*)(out + (size_t)n * HC + h * OUT_CH);
#pragma unroll
    for (int j = 0; j < 8; ++j) {
      float4 v = p[j];
      v.x *= s; v.y *= s; v.z *= s; v.w *= s;
      p[j] = v;
    }
  }
}

// blockmax -> corr (fallback path only)
__global__ __launch_bounds__(256) void reduce_corr(const unsigned* __restrict__ blockmax,
                                                   const float* __restrict__ att,
                                                   float* __restrict__ corr, int nblk) {
  __shared__ unsigned sm[HEADS];
  const int tid = threadIdx.x;
  if (tid < HEADS) sm[tid] = 0u;
  __syncthreads();
  const int h = tid & 3;
  unsigned k = 0u;
  for (int i = tid >> 2; i < nblk; i += 64) k = max(k, blockmax[i * HEADS + h]);
  atomicMax(&sm[h], k);
  __syncthreads();
  if (tid < HEADS) {
    const float Mt = unflip_f32(sm[tid]);
    float M0 = 0.f;
#pragma unroll
    for (int c = 0; c < OUT_CH; ++c) M0 += fabsf(att[tid * OUT_CH + c]);
    corr[tid] = __expf(M0 - Mt);
    corr[4 + tid] = Mt;
  }
}

// --- fallback path (ws too small): score-max pass + edge-parallel atomics ---
__global__ __launch_bounds__(256) void score_max(const float* __restrict__ proj,
                                                 const int* __restrict__ erow,
                                                 const int* __restrict__ ecol,
                                                 const float* __restrict__ att,
                                                 unsigned* __restrict__ blockmax, int E) {
  __shared__ unsigned blkmax[HEADS];
  const int tid = threadIdx.x;
  if (tid < HEADS) blkmax[tid] = 0u;
  __syncthreads();
  const int lane = tid & 63;
  const int wid = tid >> 6;
  const float a0 = att[lane];
  const float a1 = att[lane + 64];
  float lmA = -3.0e38f, lmB = -3.0e38f;
  const int stride = SCORE_BLOCKS * 16;

  for (int base = (blockIdx.x * 4 + wid) * 4; base < E; base += stride) {
    const int bu = __builtin_amdgcn_readfirstlane(base);
    const int lim = min(bu + 4, E);
    for (int e = bu; e < lim; ++e) {
      const int r0 = erow[e], c0 = ecol[e];
      const float* ps = proj + (size_t)r0 * HC;
      const float* pd = proj + (size_t)c0 * HC;
      float pA = fast_tanh(ps[lane] + pd[lane]) * a0;
      float pB = fast_tanh(ps[lane + 64] + pd[lane + 64]) * a1;
#pragma unroll
      for (int m = 16; m >= 1; m >>= 1) {
        pA += __shfl_xor(pA, m, 64);
        pB += __shfl_xor(pB, m, 64);
      }
      lmA = fmaxf(lmA, pA);
      lmB = fmaxf(lmB, pB);
    }
  }
  if ((lane & 31) == 0) {
    const int hh = lane >> 5;
    atomicMax(&blkmax[hh], flip_f32(lmA));
    atomicMax(&blkmax[hh + 2], flip_f32(lmB));
  }
  __syncthreads();
  if (tid < HEADS) blockmax[blockIdx.x * HEADS + tid] = blkmax[tid];
}

__global__ __launch_bounds__(256) void edge_apply_fb(const float* __restrict__ proj,
                                                     const int* __restrict__ erow,
                                                     const int* __restrict__ ecol,
                                                     const float* __restrict__ att,
                                                     const float* __restrict__ headmax,
                                                     float* __restrict__ out,
                                                     float* __restrict__ norm, int E) {
  const int tid = threadIdx.x;
  const int e = blockIdx.x * 2 + (tid >> 7);
  if (e >= E) return;
  const int ch = tid & 127;
  const int h = ch >> 5;
  const float M = headmax[h];
  const int row = erow[e];
  const int col = ecol[e];
  const float sv = proj[(size_t)row * HC + ch];
  const float dv = proj[(size_t)col * HC + ch];
  float p = fast_tanh(sv + dv) * att[ch];
#pragma unroll
  for (int m = 16; m >= 1; m >>= 1) p += __shfl_xor(p, m, 64);
  const float w = __expf(p - M);
  unsafeAtomicAdd(&out[(size_t)col * HC + ch], sv * w);
  if ((ch & 31) == 0) unsafeAtomicAdd(&norm[(size_t)col * HEADS + h], w);
}

__global__ __launch_bounds__(256) void finalize_fb(float* __restrict__ out,
                                                   const float* __restrict__ norm, int N) {
  const int idx = blockIdx.x * blockDim.x + threadIdx.x;
  const int total = N * (HC / 4);
  if (idx >= total) return;
  const int base = idx * 4;
  const int node = base >> 7;
  const int h = (base >> 5) & 3;
  const float inv = 1.f / fmaxf(norm[node * HEADS + h], 1e-12f);
  float4 v = ((float4*)out)[idx];
  v.x *= inv; v.y *= inv; v.z *= inv; v.w *= inv;
  ((float4*)out)[idx] = v;
}

extern "C" void kernel_launch(void* const* d_in, const int* in_sizes, int n_in,
                              void* d_out, int out_size, void* d_ws, size_t ws_size,
                              hipStream_t stream) {
  const float* x    = (const float*)d_in[0];
  const int*   eidx = (const int*)d_in[1];  // [2][E]: row(src) then col(dst)
  const float* W    = (const float*)d_in[2];
  const float* att  = (const float*)d_in[3];
  float* out = (float*)d_out;

  const int N = in_sizes[0] / IN_CH;
  const int E = in_sizes[1] / 2;
  const int nb = N;
  const int nc = (nb + CHUNK - 1) / CHUNK;  // scan chunks (<=256 supported)
  const int NB = (N + BW - 1) >> BW_SHIFT;  // buckets (<=1024 supported)
  const int ngemm = ((N + 63) / 64) * 2;    // 64-row x 64-col tiles

  // ws layout (16B-aligned pieces)
  char* p = (char*)d_ws;
  float* proj = (float*)p;  p += (size_t)N * HC * 4;
  int* rc = (int*)p;        p += (((size_t)E * 4 + 15) & ~15ull);
  float* den = (float*)p;   p += (((size_t)N * HEADS * 4 + 15) & ~15ull);
  int* hist = (int*)p;      p += (((size_t)(nb + 4 + 256 + NB) * 4 + 15) & ~15ull);
  int* starts = (int*)p;    p += (((size_t)(nb + 1) * 4 + 15) & ~15ull);
  int2* aux = (int2*)p;     p += (((size_t)E * 8 + 15) & ~15ull);
  int* sums = (int*)p;      p += 1024;
  unsigned* headmax_u = (unsigned*)(hist + nb);
  unsigned* flags = (unsigned*)(hist + nb + 4);
  int* bcnt = hist + nb + 4 + 256;
  const size_t need_full = (size_t)(p - (char*)d_ws);
  const bool full = (ws_size >= need_full) && (nc <= 256) && (NB <= 1024);

  if (full) {
    hipMemsetAsync(hist, 0, (size_t)(nb + 4 + 256 + NB) * sizeof(int), stream);
    gemm_xW<<<ngemm, 256, 0, stream>>>(x, W, proj, N, eidx + E, hist, E);
    k_scan<<<nc, 256, 0, stream>>>(hist, sums, flags, starts, nb, nc);
    bucket_split<<<(E + 2047) / 2048, 256, 0, stream>>>(eidx, eidx + E, starts,
                                                        bcnt, aux, E, NB);
    bucket_place<<<NB, 256, 0, stream>>>(aux, starts, rc, N);
    fused_apply<<<(N + 3) / 4, 256, 0, stream>>>(proj, rc, starts, att, out, den,
                                                 headmax_u, N);
    fix_clamp<<<(N * HEADS + 255) / 256, 256, 0, stream>>>(out, den, headmax_u, att, N);
  } else {
    // minimal-ws fallback: blockmax/corr/norm packed right after proj
    gemm_xW<<<ngemm, 256, 0, stream>>>(x, W, proj, N, nullptr, nullptr, 0);
    unsigned* bm = (unsigned*)(proj + (size_t)N * HC);
    float* cr = (float*)(bm + SCORE_BLOCKS * HEADS);
    float* norm = cr + 8;
    hipMemsetAsync(out, 0, (size_t)out_size * sizeof(float), stream);
    hipMemsetAsync(norm, 0, (size_t)N * HEADS * sizeof(float), stream);
    score_max<<<SCORE_BLOCKS, 256, 0, stream>>>(proj, eidx, eidx + E, att, bm, E);
    reduce_corr<<<1, 256, 0, stream>>>(bm, att, cr, SCORE_BLOCKS);
    edge_apply_fb<<<(E + 1) / 2, 256, 0, stream>>>(proj, eidx, eidx + E, att, cr + 4, out, norm, E);
    finalize_fb<<<(N * (HC / 4) + 255) / 256, 256, 0, stream>>>(out, norm, N);
  }
}

// Round 10
// 402.628 us; speedup vs baseline: 2.4238x; 1.0562x over previous
//
#include <hip/hip_runtime.h>
#include <hip/hip_fp16.h>

#define IN_CH 128
#define HEADS 4
#define OUT_CH 32
#define HC 128           // HEADS*OUT_CH
#define SCORE_BLOCKS 4096
#define CHUNK 2048       // scan chunk (256 thr x 8)
#define BW_SHIFT 9       // bucket = 512 nodes
#define BW (1 << BW_SHIFT)

__device__ __forceinline__ unsigned flip_f32(float x) {
  unsigned u = __float_as_uint(x);
  return (u & 0x80000000u) ? ~u : (u | 0x80000000u);
}
__device__ __forceinline__ float unflip_f32(unsigned k) {
  unsigned u = (k & 0x80000000u) ? (k ^ 0x80000000u) : ~k;
  return __uint_as_float(u);
}
// tanh(x) = 1 - 2/(e^{2x}+1): single v_exp_f32 + v_rcp_f32 (1-ulp).
__device__ __forceinline__ float fast_tanh(float x) {
#if __has_builtin(__builtin_amdgcn_exp2f)
  const float t = __builtin_amdgcn_exp2f(x * 2.8853900817779268f);
#else
  const float t = __expf(2.f * x);
#endif
#if __has_builtin(__builtin_amdgcn_rcpf)
  return 1.f - 2.f * __builtin_amdgcn_rcpf(t + 1.f);
#else
  return 1.f - 2.f / (t + 1.f);
#endif
}

// 8-byte fp16x4 gather -> fp32x4 (math stays fp32; storage is fp16)
__device__ __forceinline__ float4 ldh4(const __half* p) {
  const uint2 u = *(const uint2*)p;
  const float2 a = __half22float2(*(const __half2*)&u.x);
  const float2 b = __half22float2(*(const __half2*)&u.y);
  return make_float4(a.x, a.y, b.x, b.y);
}

// proj[N][128] (fp16) = x[N][128] @ W[128][128], 64x64 tiles -> 69.6KB LDS
// -> 2 blocks/CU (8 waves/CU); plus fused edge-histogram tail.
__global__ __launch_bounds__(256) void gemm_xW(const float* __restrict__ x,
                                               const float* __restrict__ W,
                                               __half* __restrict__ proj, int N,
                                               const int* __restrict__ ecol,
                                               int* __restrict__ hist, int E) {
  __shared__ float xs[128][68];  // [k][r]
  __shared__ float ws[128][68];  // [k][c]
  const int tid = threadIdx.x;
  const int rowblk = blockIdx.x >> 1;
  const int colblk = blockIdx.x & 1;
  const int row0 = rowblk * 64;
  const int col0 = colblk * 64;

  {
    const int k = tid >> 1;
    const int c0 = (tid & 1) * 32;
    const float4* src = (const float4*)(W + (size_t)k * HC + col0 + c0);
#pragma unroll
    for (int i = 0; i < 8; ++i) *(float4*)&ws[k][c0 + i * 4] = src[i];
  }
  {
    const int r = tid >> 2;
    const int k0 = (tid & 3) * 32;
    const int grow = row0 + r;
    const bool valid = grow < N;
    const float4* src = (const float4*)(x + (size_t)grow * IN_CH + k0);
#pragma unroll
    for (int i = 0; i < 8; ++i) {
      float4 v = valid ? src[i] : make_float4(0.f, 0.f, 0.f, 0.f);
      const int k = k0 + i * 4;
      xs[k][r] = v.x; xs[k + 1][r] = v.y; xs[k + 2][r] = v.z; xs[k + 3][r] = v.w;
    }
  }
  __syncthreads();

  const int cg2 = tid & 15;
  const int rg = tid >> 4;
  float acc[4][4];
#pragma unroll
  for (int r = 0; r < 4; ++r)
#pragma unroll
    for (int c = 0; c < 4; ++c) acc[r][c] = 0.f;

#pragma unroll 8
  for (int k = 0; k < 128; ++k) {
    const float4 a = *(const float4*)&xs[k][rg * 4];
    const float4 b = *(const float4*)&ws[k][cg2 * 4];
    const float xv[4] = {a.x, a.y, a.z, a.w};
    const float wv[4] = {b.x, b.y, b.z, b.w};
#pragma unroll
    for (int r = 0; r < 4; ++r)
#pragma unroll
      for (int c = 0; c < 4; ++c) acc[r][c] += xv[r] * wv[c];
  }

#pragma unroll
  for (int r = 0; r < 4; ++r) {
    const int grow = row0 + rg * 4 + r;
    if (grow < N) {
      const __half2 p0 = __floats2half2_rn(acc[r][0], acc[r][1]);
      const __half2 p1 = __floats2half2_rn(acc[r][2], acc[r][3]);
      uint2 w;
      w.x = *(const unsigned*)&p0;
      w.y = *(const unsigned*)&p1;
      *(uint2*)(proj + (size_t)grow * HC + col0 + cg2 * 4) = w;
    }
  }

  if (hist) {
    const int ehb = (E + gridDim.x - 1) / gridDim.x;
    const int estart = blockIdx.x * ehb;
    const int eend = min(estart + ehb, E);
    for (int e = estart + tid; e < eend; e += 256) atomicAdd(&hist[ecol[e]], 1);
  }
}

__device__ __forceinline__ int block_scan_excl(int tsum, int* ls, int tid, int* total) {
  ls[tid] = tsum;
  __syncthreads();
  for (int off = 1; off < 256; off <<= 1) {
    int v = (tid >= off) ? ls[tid - off] : 0;
    __syncthreads();
    ls[tid] += v;
    __syncthreads();
  }
  *total = ls[255];
  return ls[tid] - tsum;
}

// Single-pass scan with release/acquire flag handshake (no coop grid.sync).
__global__ __launch_bounds__(256) void k_scan(const int* __restrict__ hist,
                                              int* __restrict__ sums,
                                              unsigned* __restrict__ flags,
                                              int* __restrict__ starts,
                                              int nb, int nc) {
  __shared__ int ls[256];
  const int tid = threadIdx.x;
  const int bid = blockIdx.x;
  const int base = bid * CHUNK + tid * 8;
  int h[8];
  int t = 0;
#pragma unroll
  for (int j = 0; j < 8; ++j) {
    const int i = base + j;
    h[j] = (i < nb) ? hist[i] : 0;
    t += h[j];
  }
  int total;
  const int excl = block_scan_excl(t, ls, tid, &total);
  if (tid == 0) {
    __hip_atomic_store(&sums[bid], total, __ATOMIC_RELAXED, __HIP_MEMORY_SCOPE_AGENT);
    __hip_atomic_store(&flags[bid], 1u, __ATOMIC_RELEASE, __HIP_MEMORY_SCOPE_AGENT);
  }
  int my = 0;
  if (tid < bid) {
    while (__hip_atomic_load(&flags[tid], __ATOMIC_ACQUIRE, __HIP_MEMORY_SCOPE_AGENT) == 0u) {}
    my = __hip_atomic_load(&sums[tid], __ATOMIC_RELAXED, __HIP_MEMORY_SCOPE_AGENT);
  }
  __syncthreads();  // all spins done; ls free for reuse
  ls[tid] = my;
  __syncthreads();
  for (int off = 128; off >= 1; off >>= 1) {
    if (tid < off) ls[tid] += ls[tid + off];
    __syncthreads();
  }
  const int cbase = ls[0];
  int run = cbase + excl;
#pragma unroll
  for (int j = 0; j < 8; ++j) {
    const int i = base + j;
    if (i < nb) { starts[i] = run; run += h[j]; }
  }
  if (bid == nc - 1 && tid == 0) starts[nb] = cbase + total;
}

// Phase A: LDS multisplit of edges into per-bucket aux regions.
__global__ __launch_bounds__(256) void bucket_split(const int* __restrict__ erow,
                                                    const int* __restrict__ ecol,
                                                    const int* __restrict__ starts,
                                                    int* __restrict__ bcnt,
                                                    int2* __restrict__ aux,
                                                    int E, int NB) {
  __shared__ int cnt[1024];
  __shared__ int base[1024];
  const int tid = threadIdx.x;
  for (int b = tid; b < NB; b += 256) cnt[b] = 0;
  __syncthreads();
  const int e0 = blockIdx.x * 2048;
  int rows[8], cols[8], loc[8];
#pragma unroll
  for (int j = 0; j < 8; ++j) {
    const int e = e0 + j * 256 + tid;
    if (e < E) {
      cols[j] = ecol[e];
      rows[j] = erow[e];
      loc[j] = atomicAdd(&cnt[cols[j] >> BW_SHIFT], 1);
    } else {
      loc[j] = -1;
    }
  }
  __syncthreads();
  for (int b = tid; b < NB; b += 256) {
    const int c = cnt[b];
    base[b] = (c ? atomicAdd(&bcnt[b], c) : 0) + starts[b << BW_SHIFT];
  }
  __syncthreads();
#pragma unroll
  for (int j = 0; j < 8; ++j) {
    if (loc[j] >= 0) {
      const int b = cols[j] >> BW_SHIFT;
      aux[base[b] + loc[j]] = make_int2(rows[j] * HC, cols[j]);
    }
  }
}

// Phase B: one block per bucket; LDS per-node rank counters.
__global__ __launch_bounds__(256) void bucket_place(const int2* __restrict__ aux,
                                                    const int* __restrict__ starts,
                                                    int* __restrict__ rc, int N) {
  __shared__ int lcnt[BW];
  const int tid = threadIdx.x;
  const int n0 = blockIdx.x << BW_SHIFT;
  const int n1 = min(n0 + BW, N);
  for (int i = tid; i < BW; i += 256) lcnt[i] = 0;
  __syncthreads();
  const int e0 = starts[n0];
  const int e1 = starts[n1];
  for (int i = e0 + tid; i < e1; i += 256) {
    const int2 pr = aux[i];
    const int r = atomicAdd(&lcnt[pr.y & (BW - 1)], 1);
    rc[starts[pr.y] + r] = pr.x;
  }
}

// Wave per dst node, HALF-WAVE per edge, 8-edge main unroll; fp16 proj gathers
// (halved FETCH), fp32 math throughout.
__global__ __launch_bounds__(256) void fused_apply(const __half* __restrict__ proj,
                                                   const int* __restrict__ rc,
                                                   const int* __restrict__ starts,
                                                   const float* __restrict__ att,
                                                   float* __restrict__ out,
                                                   float* __restrict__ den,
                                                   unsigned* __restrict__ headmax_u, int N) {
  __shared__ unsigned blkmax[HEADS];
  const int tid = threadIdx.x;
  if (tid < HEADS) blkmax[tid] = 0u;
  __syncthreads();
  const int lane = tid & 63;
  const int half = lane >> 5;
  const int l = lane & 31;
  const int c0 = l * 4;
  const int head = l >> 3;
  const int n = blockIdx.x * 4 + (tid >> 6);
  float lm = -3.0e38f;

  if (n < N) {
    const float4 a4 = ((const float4*)att)[l];
    float M0 = fabsf(a4.x) + fabsf(a4.y) + fabsf(a4.z) + fabsf(a4.w);
    M0 += __shfl_xor(M0, 4, 64);
    M0 += __shfl_xor(M0, 2, 64);
    M0 += __shfl_xor(M0, 1, 64);
    const float4 d4 = ldh4(proj + (size_t)n * HC + c0);
    const int beg = __builtin_amdgcn_readfirstlane(starts[n]);
    const int end = __builtin_amdgcn_readfirstlane(starts[n + 1]);

    float ax = 0.f, ay = 0.f, az = 0.f, aw = 0.f, dsum = 0.f;
    int i = beg;
    for (; i + 8 <= end; i += 8) {
      const int r0 = rc[i + half];
      const int r1 = rc[i + 2 + half];
      const int r2 = rc[i + 4 + half];
      const int r3 = rc[i + 6 + half];
      const float4 s0 = ldh4(proj + r0 + c0);
      const float4 s1 = ldh4(proj + r1 + c0);
      const float4 s2 = ldh4(proj + r2 + c0);
      const float4 s3 = ldh4(proj + r3 + c0);
      float p0 = fast_tanh(s0.x + d4.x) * a4.x + fast_tanh(s0.y + d4.y) * a4.y
               + fast_tanh(s0.z + d4.z) * a4.z + fast_tanh(s0.w + d4.w) * a4.w;
      float p1 = fast_tanh(s1.x + d4.x) * a4.x + fast_tanh(s1.y + d4.y) * a4.y
               + fast_tanh(s1.z + d4.z) * a4.z + fast_tanh(s1.w + d4.w) * a4.w;
      float p2 = fast_tanh(s2.x + d4.x) * a4.x + fast_tanh(s2.y + d4.y) * a4.y
               + fast_tanh(s2.z + d4.z) * a4.z + fast_tanh(s2.w + d4.w) * a4.w;
      float p3 = fast_tanh(s3.x + d4.x) * a4.x + fast_tanh(s3.y + d4.y) * a4.y
               + fast_tanh(s3.z + d4.z) * a4.z + fast_tanh(s3.w + d4.w) * a4.w;
      p0 += __shfl_xor(p0, 4, 64);  p1 += __shfl_xor(p1, 4, 64);
      p2 += __shfl_xor(p2, 4, 64);  p3 += __shfl_xor(p3, 4, 64);
      p0 += __shfl_xor(p0, 2, 64);  p1 += __shfl_xor(p1, 2, 64);
      p2 += __shfl_xor(p2, 2, 64);  p3 += __shfl_xor(p3, 2, 64);
      p0 += __shfl_xor(p0, 1, 64);  p1 += __shfl_xor(p1, 1, 64);
      p2 += __shfl_xor(p2, 1, 64);  p3 += __shfl_xor(p3, 1, 64);
      lm = fmaxf(lm, fmaxf(fmaxf(p0, p1), fmaxf(p2, p3)));
      const float e0 = __expf(p0 - M0);
      const float e1 = __expf(p1 - M0);
      const float e2 = __expf(p2 - M0);
      const float e3 = __expf(p3 - M0);
      ax += s0.x * e0 + s1.x * e1 + s2.x * e2 + s3.x * e3;
      ay += s0.y * e0 + s1.y * e1 + s2.y * e2 + s3.y * e3;
      az += s0.z * e0 + s1.z * e1 + s2.z * e2 + s3.z * e3;
      aw += s0.w * e0 + s1.w * e1 + s2.w * e2 + s3.w * e3;
      dsum += (e0 + e1) + (e2 + e3);
    }
    if (i + 4 <= end) {
      const int r0 = rc[i + half];
      const int r1 = rc[i + 2 + half];
      const float4 s0 = ldh4(proj + r0 + c0);
      const float4 s1 = ldh4(proj + r1 + c0);
      float p0 = fast_tanh(s0.x + d4.x) * a4.x + fast_tanh(s0.y + d4.y) * a4.y
               + fast_tanh(s0.z + d4.z) * a4.z + fast_tanh(s0.w + d4.w) * a4.w;
      float p1 = fast_tanh(s1.x + d4.x) * a4.x + fast_tanh(s1.y + d4.y) * a4.y
               + fast_tanh(s1.z + d4.z) * a4.z + fast_tanh(s1.w + d4.w) * a4.w;
      p0 += __shfl_xor(p0, 4, 64);  p1 += __shfl_xor(p1, 4, 64);
      p0 += __shfl_xor(p0, 2, 64);  p1 += __shfl_xor(p1, 2, 64);
      p0 += __shfl_xor(p0, 1, 64);  p1 += __shfl_xor(p1, 1, 64);
      lm = fmaxf(lm, fmaxf(p0, p1));
      const float e0 = __expf(p0 - M0);
      const float e1 = __expf(p1 - M0);
      ax += s0.x * e0 + s1.x * e1;
      ay += s0.y * e0 + s1.y * e1;
      az += s0.z * e0 + s1.z * e1;
      aw += s0.w * e0 + s1.w * e1;
      dsum += e0 + e1;
      i += 4;
    }
    for (; i < end; i += 2) {
      const int idx = i + half;
      const bool valid = idx < end;
      const int row = rc[valid ? idx : i];
      const float4 s4 = ldh4(proj + row + c0);
      float p = fast_tanh(s4.x + d4.x) * a4.x
              + fast_tanh(s4.y + d4.y) * a4.y
              + fast_tanh(s4.z + d4.z) * a4.z
              + fast_tanh(s4.w + d4.w) * a4.w;
      p += __shfl_xor(p, 4, 64);
      p += __shfl_xor(p, 2, 64);
      p += __shfl_xor(p, 1, 64);
      if (!valid) p = -3.0e38f;
      lm = fmaxf(lm, p);
      const float e = __expf(p - M0);
      ax += s4.x * e; ay += s4.y * e; az += s4.z * e; aw += s4.w * e;
      dsum += e;
    }
    dsum += __shfl_xor(dsum, 32, 64);
    ax += __shfl_xor(ax, 32, 64);
    ay += __shfl_xor(ay, 32, 64);
    az += __shfl_xor(az, 32, 64);
    aw += __shfl_xor(aw, 32, 64);
    lm = fmaxf(lm, __shfl_xor(lm, 32, 64));
    if (half == 0) {
      const float inv = 1.f / fmaxf(dsum, 1e-38f);
      *(float4*)(out + (size_t)n * HC + c0) =
          make_float4(ax * inv, ay * inv, az * inv, aw * inv);
      if ((l & 7) == 0) den[n * HEADS + head] = dsum;
      if ((l & 7) == 0) atomicMax(&blkmax[head], flip_f32(lm));
    }
  }
  __syncthreads();
  if (tid < HEADS) {
    const unsigned v = blkmax[tid];
    if (v > headmax_u[tid]) atomicMax(&headmax_u[tid], v);
  }
}

// Reference normalizer = den * exp(M0_h - Mt_h). If below 1e-12 the reference
// clamps: out_ref = out_ours * (ref_den / 1e-12).
__global__ __launch_bounds__(256) void fix_clamp(float* __restrict__ out,
                                                 const float* __restrict__ den,
                                                 const unsigned* __restrict__ headmax_u,
                                                 const float* __restrict__ att, int N) {
  const int t = blockIdx.x * 256 + threadIdx.x;
  if (t >= N * HEADS) return;
  const int n = t >> 2;
  const int h = t & 3;
  float M0 = 0.f;
#pragma unroll
  for (int c = 0; c < OUT_CH; ++c) M0 += fabsf(att[h * OUT_CH + c]);
  const float Mt = unflip_f32(headmax_u[h]);
  const float f = den[t] * __expf(M0 - Mt);
  if (f < 1e-12f) {
    const float s = f * 1e12f;
    float4* p = (float4*)(out + (size_t)n * HC + h * OUT_CH);
#pragma unroll
    for (int j = 0; j < 8; ++j) {
      float4 v = p[j];
      v.x *= s; v.y *= s; v.z *= s; v.w *= s;
      p[j] = v;
    }
  }
}

// blockmax -> corr (fallback path only)
__global__ __launch_bounds__(256) void reduce_corr(const unsigned* __restrict__ blockmax,
                                                   const float* __restrict__ att,
                                                   float* __restrict__ corr, int nblk) {
  __shared__ unsigned sm[HEADS];
  const int tid = threadIdx.x;
  if (tid < HEADS) sm[tid] = 0u;
  __syncthreads();
  const int h = tid & 3;
  unsigned k = 0u;
  for (int i = tid >> 2; i < nblk; i += 64) k = max(k, blockmax[i * HEADS + h]);
  atomicMax(&sm[h], k);
  __syncthreads();
  if (tid < HEADS) {
    const float Mt = unflip_f32(sm[tid]);
    float M0 = 0.f;
#pragma unroll
    for (int c = 0; c < OUT_CH; ++c) M0 += fabsf(att[tid * OUT_CH + c]);
    corr[tid] = __expf(M0 - Mt);
    corr[4 + tid] = Mt;
  }
}

// --- fallback path (ws too small): score-max pass + edge-parallel atomics ---
__global__ __launch_bounds__(256) void score_max(const __half* __restrict__ proj,
                                                 const int* __restrict__ erow,
                                                 const int* __restrict__ ecol,
                                                 const float* __restrict__ att,
                                                 unsigned* __restrict__ blockmax, int E) {
  __shared__ unsigned blkmax[HEADS];
  const int tid = threadIdx.x;
  if (tid < HEADS) blkmax[tid] = 0u;
  __syncthreads();
  const int lane = tid & 63;
  const int wid = tid >> 6;
  const float a0 = att[lane];
  const float a1 = att[lane + 64];
  float lmA = -3.0e38f, lmB = -3.0e38f;
  const int stride = SCORE_BLOCKS * 16;

  for (int base = (blockIdx.x * 4 + wid) * 4; base < E; base += stride) {
    const int bu = __builtin_amdgcn_readfirstlane(base);
    const int lim = min(bu + 4, E);
    for (int e = bu; e < lim; ++e) {
      const int r0 = erow[e], c0 = ecol[e];
      const __half* ps = proj + (size_t)r0 * HC;
      const __half* pd = proj + (size_t)c0 * HC;
      float pA = fast_tanh(__half2float(ps[lane]) + __half2float(pd[lane])) * a0;
      float pB = fast_tanh(__half2float(ps[lane + 64]) + __half2float(pd[lane + 64])) * a1;
#pragma unroll
      for (int m = 16; m >= 1; m >>= 1) {
        pA += __shfl_xor(pA, m, 64);
        pB += __shfl_xor(pB, m, 64);
      }
      lmA = fmaxf(lmA, pA);
      lmB = fmaxf(lmB, pB);
    }
  }
  if ((lane & 31) == 0) {
    const int hh = lane >> 5;
    atomicMax(&blkmax[hh], flip_f32(lmA));
    atomicMax(&blkmax[hh + 2], flip_f32(lmB));
  }
  __syncthreads();
  if (tid < HEADS) blockmax[blockIdx.x * HEADS + tid] = blkmax[tid];
}

__global__ __launch_bounds__(256) void edge_apply_fb(const __half* __restrict__ proj,
                                                     const int* __restrict__ erow,
                                                     const int* __restrict__ ecol,
                                                     const float* __restrict__ att,
                                                     const float* __restrict__ headmax,
                                                     float* __restrict__ out,
                                                     float* __restrict__ norm, int E) {
  const int tid = threadIdx.x;
  const int e = blockIdx.x * 2 + (tid >> 7);
  if (e >= E) return;
  const int ch = tid & 127;
  const int h = ch >> 5;
  const float M = headmax[h];
  const int row = erow[e];
  const int col = ecol[e];
  const float sv = __half2float(proj[(size_t)row * HC + ch]);
  const float dv = __half2float(proj[(size_t)col * HC + ch]);
  float p = fast_tanh(sv + dv) * att[ch];
#pragma unroll
  for (int m = 16; m >= 1; m >>= 1) p += __shfl_xor(p, m, 64);
  const float w = __expf(p - M);
  unsafeAtomicAdd(&out[(size_t)col * HC + ch], sv * w);
  if ((ch & 31) == 0) unsafeAtomicAdd(&norm[(size_t)col * HEADS + h], w);
}

__global__ __launch_bounds__(256) void finalize_fb(float* __restrict__ out,
                                                   const float* __restrict__ norm, int N) {
  const int idx = blockIdx.x * blockDim.x + threadIdx.x;
  const int total = N * (HC / 4);
  if (idx >= total) return;
  const int base = idx * 4;
  const int node = base >> 7;
  const int h = (base >> 5) & 3;
  const float inv = 1.f / fmaxf(norm[node * HEADS + h], 1e-12f);
  float4 v = ((float4*)out)[idx];
  v.x *= inv; v.y *= inv; v.z *= inv; v.w *= inv;
  ((float4*)out)[idx] = v;
}

extern "C" void kernel_launch(void* const* d_in, const int* in_sizes, int n_in,
                              void* d_out, int out_size, void* d_ws, size_t ws_size,
                              hipStream_t stream) {
  const float* x    = (const float*)d_in[0];
  const int*   eidx = (const int*)d_in[1];  // [2][E]: row(src) then col(dst)
  const float* W    = (const float*)d_in[2];
  const float* att  = (const float*)d_in[3];
  float* out = (float*)d_out;

  const int N = in_sizes[0] / IN_CH;
  const int E = in_sizes[1] / 2;
  const int nb = N;
  const int nc = (nb + CHUNK - 1) / CHUNK;  // scan chunks (<=256 supported)
  const int NB = (N + BW - 1) >> BW_SHIFT;  // buckets (<=1024 supported)
  const int ngemm = ((N + 63) / 64) * 2;    // 64-row x 64-col tiles

  // ws layout (16B-aligned pieces)
  char* p = (char*)d_ws;
  __half* proj = (__half*)p;  p += (((size_t)N * HC * 2 + 15) & ~15ull);
  int* rc = (int*)p;        p += (((size_t)E * 4 + 15) & ~15ull);
  float* den = (float*)p;   p += (((size_t)N * HEADS * 4 + 15) & ~15ull);
  int* hist = (int*)p;      p += (((size_t)(nb + 4 + 256 + NB) * 4 + 15) & ~15ull);
  int* starts = (int*)p;    p += (((size_t)(nb + 1) * 4 + 15) & ~15ull);
  int2* aux = (int2*)p;     p += (((size_t)E * 8 + 15) & ~15ull);
  int* sums = (int*)p;      p += 1024;
  unsigned* headmax_u = (unsigned*)(hist + nb);
  unsigned* flags = (unsigned*)(hist + nb + 4);
  int* bcnt = hist + nb + 4 + 256;
  const size_t need_full = (size_t)(p - (char*)d_ws);
  const bool full = (ws_size >= need_full) && (nc <= 256) && (NB <= 1024);

  if (full) {
    hipMemsetAsync(hist, 0, (size_t)(nb + 4 + 256 + NB) * sizeof(int), stream);
    gemm_xW<<<ngemm, 256, 0, stream>>>(x, W, proj, N, eidx + E, hist, E);
    k_scan<<<nc, 256, 0, stream>>>(hist, sums, flags, starts, nb, nc);
    bucket_split<<<(E + 2047) / 2048, 256, 0, stream>>>(eidx, eidx + E, starts,
                                                        bcnt, aux, E, NB);
    bucket_place<<<NB, 256, 0, stream>>>(aux, starts, rc, N);
    fused_apply<<<(N + 3) / 4, 256, 0, stream>>>(proj, rc, starts, att, out, den,
                                                 headmax_u, N);
    fix_clamp<<<(N * HEADS + 255) / 256, 256, 0, stream>>>(out, den, headmax_u, att, N);
  } else {
    // minimal-ws fallback: blockmax/corr/norm packed right after proj
    gemm_xW<<<ngemm, 256, 0, stream>>>(x, W, proj, N, nullptr, nullptr, 0);
    unsigned* bm = (unsigned*)((char*)d_ws + (((size_t)N * HC * 2 + 15) & ~15ull));
    float* cr = (float*)(bm + SCORE_BLOCKS * HEADS);
    float* norm = cr + 8;
    hipMemsetAsync(out, 0, (size_t)out_size * sizeof(float), stream);
    hipMemsetAsync(norm, 0, (size_t)N * HEADS * sizeof(float), stream);
    score_max<<<SCORE_BLOCKS, 256, 0, stream>>>(proj, eidx, eidx + E, att, bm, E);
    reduce_corr<<<1, 256, 0, stream>>>(bm, att, cr, SCORE_BLOCKS);
    edge_apply_fb<<<(E + 1) / 2, 256, 0, stream>>>(proj, eidx, eidx + E, att, cr + 4, out, norm, E);
    finalize_fb<<<(N * (HC / 4) + 255) / 256, 256, 0, stream>>>(out, norm, N);
  }
}

// Round 11
// 379.290 us; speedup vs baseline: 2.5730x; 1.0615x over previous
//
#include <hip/hip_runtime.h>
#include <hip/hip_fp16.h>

#define IN_CH 128
#define HEADS 4
#define OUT_CH 32
#define HC 128           // HEADS*OUT_CH
#define SCORE_BLOCKS 4096
#define BW_SHIFT 9       // bucket = 512 nodes
#define BW (1 << BW_SHIFT)

__device__ __forceinline__ unsigned flip_f32(float x) {
  unsigned u = __float_as_uint(x);
  return (u & 0x80000000u) ? ~u : (u | 0x80000000u);
}
__device__ __forceinline__ float unflip_f32(unsigned k) {
  unsigned u = (k & 0x80000000u) ? (k ^ 0x80000000u) : ~k;
  return __uint_as_float(u);
}
__device__ __forceinline__ float fexp2(float x) {
#if __has_builtin(__builtin_amdgcn_exp2f)
  return __builtin_amdgcn_exp2f(x);
#else
  return exp2f(x);
#endif
}
__device__ __forceinline__ float frcp(float x) {
#if __has_builtin(__builtin_amdgcn_rcpf)
  return __builtin_amdgcn_rcpf(x);
#else
  return 1.f / x;
#endif
}
// tanh via single exp2 + rcp (fallback kernels only)
__device__ __forceinline__ float fast_tanh(float x) {
  return 1.f - 2.f * frcp(fexp2(x * 2.8853900817779268f) + 1.f);
}

// Sum_c a_c * tanh(s_c + d_c) with ONE rcp for all 4 channels (exact algebra):
// Sum a_c (1 - 2/(t_c+1)) = A - 2 * [ (a0*t1+a1*t0)*p23 + (a2*t3+a3*t2)*p01 ] / D
// where t_c = e^{2x_c}, p01=t0*t1, p23=t2*t3, D=p01*p23, A=Sum a_c.
// Trans ops per call: 4 exp2 + 1 rcp (was 4 exp2 + 4 rcp).
__device__ __forceinline__ float att_tanh_dot(float4 s, float4 d, float4 a, float A) {
  const float K = 2.8853900817779268f;  // 2*log2(e)
  const float t0 = fexp2((s.x + d.x) * K) + 1.f;
  const float t1 = fexp2((s.y + d.y) * K) + 1.f;
  const float t2 = fexp2((s.z + d.z) * K) + 1.f;
  const float t3 = fexp2((s.w + d.w) * K) + 1.f;
  const float p01 = t0 * t1, p23 = t2 * t3;
  const float R = frcp(p01 * p23);
  const float n01 = a.x * t1 + a.y * t0;
  const float n23 = a.z * t3 + a.w * t2;
  const float num = n01 * p23 + n23 * p01;
  return A - 2.f * num * R;
}

// 8-byte fp16x4 gather -> fp32x4 (math stays fp32; storage is fp16)
__device__ __forceinline__ float4 ldh4(const __half* p) {
  const uint2 u = *(const uint2*)p;
  const float2 a = __half22float2(*(const __half2*)&u.x);
  const float2 b = __half22float2(*(const __half2*)&u.y);
  return make_float4(a.x, a.y, b.x, b.y);
}

// proj[N][128] (fp16) = x[N][128] @ W[128][128], 64x64 tiles (69.6+4KB LDS,
// 2 blocks/CU); fused PER-BUCKET edge count tail (LDS histogram, NB global
// atomics/block -- replaces the old 1.6M random global atomic per-node hist).
__global__ __launch_bounds__(256) void gemm_xW(const float* __restrict__ x,
                                               const float* __restrict__ W,
                                               __half* __restrict__ proj, int N,
                                               const int* __restrict__ ecol,
                                               int* __restrict__ bcnt0, int E, int NB) {
  __shared__ float xs[128][68];  // [k][r]
  __shared__ float ws[128][68];  // [k][c]
  __shared__ int cnt[1024];
  const int tid = threadIdx.x;
  const int rowblk = blockIdx.x >> 1;
  const int colblk = blockIdx.x & 1;
  const int row0 = rowblk * 64;
  const int col0 = colblk * 64;

  {
    const int k = tid >> 1;
    const int c0 = (tid & 1) * 32;
    const float4* src = (const float4*)(W + (size_t)k * HC + col0 + c0);
#pragma unroll
    for (int i = 0; i < 8; ++i) *(float4*)&ws[k][c0 + i * 4] = src[i];
  }
  {
    const int r = tid >> 2;
    const int k0 = (tid & 3) * 32;
    const int grow = row0 + r;
    const bool valid = grow < N;
    const float4* src = (const float4*)(x + (size_t)grow * IN_CH + k0);
#pragma unroll
    for (int i = 0; i < 8; ++i) {
      float4 v = valid ? src[i] : make_float4(0.f, 0.f, 0.f, 0.f);
      const int k = k0 + i * 4;
      xs[k][r] = v.x; xs[k + 1][r] = v.y; xs[k + 2][r] = v.z; xs[k + 3][r] = v.w;
    }
  }
  if (bcnt0) {
    for (int b = tid; b < NB; b += 256) cnt[b] = 0;
  }
  __syncthreads();

  const int cg2 = tid & 15;
  const int rg = tid >> 4;
  float acc[4][4];
#pragma unroll
  for (int r = 0; r < 4; ++r)
#pragma unroll
    for (int c = 0; c < 4; ++c) acc[r][c] = 0.f;

#pragma unroll 8
  for (int k = 0; k < 128; ++k) {
    const float4 a = *(const float4*)&xs[k][rg * 4];
    const float4 b = *(const float4*)&ws[k][cg2 * 4];
    const float xv[4] = {a.x, a.y, a.z, a.w};
    const float wv[4] = {b.x, b.y, b.z, b.w};
#pragma unroll
    for (int r = 0; r < 4; ++r)
#pragma unroll
      for (int c = 0; c < 4; ++c) acc[r][c] += xv[r] * wv[c];
  }

#pragma unroll
  for (int r = 0; r < 4; ++r) {
    const int grow = row0 + rg * 4 + r;
    if (grow < N) {
      const __half2 p0 = __floats2half2_rn(acc[r][0], acc[r][1]);
      const __half2 p1 = __floats2half2_rn(acc[r][2], acc[r][3]);
      uint2 w;
      w.x = *(const unsigned*)&p0;
      w.y = *(const unsigned*)&p1;
      *(uint2*)(proj + (size_t)grow * HC + col0 + cg2 * 4) = w;
    }
  }

  if (bcnt0) {
    const int ehb = (E + gridDim.x - 1) / gridDim.x;
    const int estart = blockIdx.x * ehb;
    const int eend = min(estart + ehb, E);
    for (int e = estart + tid; e < eend; e += 256)
      atomicAdd(&cnt[ecol[e] >> BW_SHIFT], 1);
    __syncthreads();
    for (int b = tid; b < NB; b += 256) {
      const int c = cnt[b];
      if (c) atomicAdd(&bcnt0[b], c);
    }
  }
}

__device__ __forceinline__ int block_scan_excl(int tsum, int* ls, int tid, int* total) {
  ls[tid] = tsum;
  __syncthreads();
  for (int off = 1; off < 256; off <<= 1) {
    int v = (tid >= off) ? ls[tid - off] : 0;
    __syncthreads();
    ls[tid] += v;
    __syncthreads();
  }
  *total = ls[255];
  return ls[tid] - tsum;
}

// One block: exclusive scan of NB (<=1024) bucket totals -> bstarts[0..NB].
__global__ __launch_bounds__(256) void bucket_scan(const int* __restrict__ bcnt0,
                                                   int* __restrict__ bstarts, int NB) {
  __shared__ int ls[256];
  const int tid = threadIdx.x;
  int v[4];
  int t = 0;
#pragma unroll
  for (int j = 0; j < 4; ++j) {
    const int idx = tid * 4 + j;
    v[j] = (idx < NB) ? bcnt0[idx] : 0;
    t += v[j];
  }
  int total;
  int run = block_scan_excl(t, ls, tid, &total);
#pragma unroll
  for (int j = 0; j < 4; ++j) {
    const int idx = tid * 4 + j;
    if (idx < NB) { bstarts[idx] = run; run += v[j]; }
  }
  if (tid == 0) bstarts[NB] = total;  // == E
}

// Phase A: LDS multisplit of edges into per-bucket aux regions
// [bstarts[b], bstarts[b+1]) -- exact sizes, contiguous per-block runs.
__global__ __launch_bounds__(256) void bucket_split(const int* __restrict__ erow,
                                                    const int* __restrict__ ecol,
                                                    const int* __restrict__ bstarts,
                                                    int* __restrict__ bcnt,
                                                    int2* __restrict__ aux,
                                                    int E, int NB) {
  __shared__ int cnt[1024];
  __shared__ int base[1024];
  const int tid = threadIdx.x;
  for (int b = tid; b < NB; b += 256) cnt[b] = 0;
  __syncthreads();
  const int e0 = blockIdx.x * 2048;
  int rows[8], cols[8], loc[8];
#pragma unroll
  for (int j = 0; j < 8; ++j) {
    const int e = e0 + j * 256 + tid;
    if (e < E) {
      cols[j] = ecol[e];
      rows[j] = erow[e];
      loc[j] = atomicAdd(&cnt[cols[j] >> BW_SHIFT], 1);
    } else {
      loc[j] = -1;
    }
  }
  __syncthreads();
  for (int b = tid; b < NB; b += 256) {
    const int c = cnt[b];
    base[b] = (c ? atomicAdd(&bcnt[b], c) : 0) + bstarts[b];
  }
  __syncthreads();
#pragma unroll
  for (int j = 0; j < 8; ++j) {
    if (loc[j] >= 0) {
      const int b = cols[j] >> BW_SHIFT;
      aux[base[b] + loc[j]] = make_int2(rows[j] * HC, cols[j]);
    }
  }
}

// Phase B: one block per bucket. Pass 1: LDS per-node count + scan -> writes
// global starts[] for its 512 nodes (replaces the old per-node hist+k_scan).
// Pass 2: rank-place rc. All writes land in one contiguous region.
__global__ __launch_bounds__(256) void bucket_place(const int2* __restrict__ aux,
                                                    const int* __restrict__ bstarts,
                                                    int* __restrict__ starts,
                                                    int* __restrict__ rc, int N, int NB) {
  __shared__ int lcnt[BW];
  __shared__ int ls[256];
  const int tid = threadIdx.x;
  const int b = blockIdx.x;
  const int n0 = b << BW_SHIFT;
  const int n1 = min(n0 + BW, N);
  const int e0 = bstarts[b];
  const int e1 = bstarts[b + 1];
  for (int i = tid; i < BW; i += 256) lcnt[i] = 0;
  __syncthreads();
  for (int i = e0 + tid; i < e1; i += 256)
    atomicAdd(&lcnt[aux[i].y & (BW - 1)], 1);
  __syncthreads();
  const int c0 = lcnt[2 * tid];
  const int c1 = lcnt[2 * tid + 1];
  int total;
  const int excl = block_scan_excl(c0 + c1, ls, tid, &total);
  const int n = n0 + 2 * tid;
  if (n < n1) starts[n] = e0 + excl;
  if (n + 1 < n1) starts[n + 1] = e0 + excl + c0;
  lcnt[2 * tid] = e0 + excl;          // becomes the write cursor
  lcnt[2 * tid + 1] = e0 + excl + c0;
  if (b == NB - 1 && tid == 0) starts[N] = e1;  // == E
  __syncthreads();
  for (int i = e0 + tid; i < e1; i += 256) {
    const int2 pr = aux[i];
    const int r = atomicAdd(&lcnt[pr.y & (BW - 1)], 1);
    rc[r] = pr.x;
  }
}

// Wave per dst node, HALF-WAVE per edge, 8-edge main unroll; fp16 proj gathers,
// fp32 math, 4-way-combined rcp in the score dot (att_tanh_dot).
__global__ __launch_bounds__(256) void fused_apply(const __half* __restrict__ proj,
                                                   const int* __restrict__ rc,
                                                   const int* __restrict__ starts,
                                                   const float* __restrict__ att,
                                                   float* __restrict__ out,
                                                   float* __restrict__ den,
                                                   unsigned* __restrict__ headmax_u, int N) {
  __shared__ unsigned blkmax[HEADS];
  const int tid = threadIdx.x;
  if (tid < HEADS) blkmax[tid] = 0u;
  __syncthreads();
  const int lane = tid & 63;
  const int half = lane >> 5;
  const int l = lane & 31;
  const int c0 = l * 4;
  const int head = l >> 3;
  const int n = blockIdx.x * 4 + (tid >> 6);
  float lm = -3.0e38f;

  if (n < N) {
    const float4 a4 = ((const float4*)att)[l];
    const float A = ((a4.x + a4.y) + (a4.z + a4.w));
    float M0 = fabsf(a4.x) + fabsf(a4.y) + fabsf(a4.z) + fabsf(a4.w);
    M0 += __shfl_xor(M0, 4, 64);
    M0 += __shfl_xor(M0, 2, 64);
    M0 += __shfl_xor(M0, 1, 64);
    const float4 d4 = ldh4(proj + (size_t)n * HC + c0);
    const int beg = __builtin_amdgcn_readfirstlane(starts[n]);
    const int end = __builtin_amdgcn_readfirstlane(starts[n + 1]);

    float ax = 0.f, ay = 0.f, az = 0.f, aw = 0.f, dsum = 0.f;
    int i = beg;
    for (; i + 8 <= end; i += 8) {
      const int r0 = rc[i + half];
      const int r1 = rc[i + 2 + half];
      const int r2 = rc[i + 4 + half];
      const int r3 = rc[i + 6 + half];
      const float4 s0 = ldh4(proj + r0 + c0);
      const float4 s1 = ldh4(proj + r1 + c0);
      const float4 s2 = ldh4(proj + r2 + c0);
      const float4 s3 = ldh4(proj + r3 + c0);
      float p0 = att_tanh_dot(s0, d4, a4, A);
      float p1 = att_tanh_dot(s1, d4, a4, A);
      float p2 = att_tanh_dot(s2, d4, a4, A);
      float p3 = att_tanh_dot(s3, d4, a4, A);
      p0 += __shfl_xor(p0, 4, 64);  p1 += __shfl_xor(p1, 4, 64);
      p2 += __shfl_xor(p2, 4, 64);  p3 += __shfl_xor(p3, 4, 64);
      p0 += __shfl_xor(p0, 2, 64);  p1 += __shfl_xor(p1, 2, 64);
      p2 += __shfl_xor(p2, 2, 64);  p3 += __shfl_xor(p3, 2, 64);
      p0 += __shfl_xor(p0, 1, 64);  p1 += __shfl_xor(p1, 1, 64);
      p2 += __shfl_xor(p2, 1, 64);  p3 += __shfl_xor(p3, 1, 64);
      lm = fmaxf(lm, fmaxf(fmaxf(p0, p1), fmaxf(p2, p3)));
      const float e0 = __expf(p0 - M0);
      const float e1 = __expf(p1 - M0);
      const float e2 = __expf(p2 - M0);
      const float e3 = __expf(p3 - M0);
      ax += s0.x * e0 + s1.x * e1 + s2.x * e2 + s3.x * e3;
      ay += s0.y * e0 + s1.y * e1 + s2.y * e2 + s3.y * e3;
      az += s0.z * e0 + s1.z * e1 + s2.z * e2 + s3.z * e3;
      aw += s0.w * e0 + s1.w * e1 + s2.w * e2 + s3.w * e3;
      dsum += (e0 + e1) + (e2 + e3);
    }
    if (i + 4 <= end) {
      const int r0 = rc[i + half];
      const int r1 = rc[i + 2 + half];
      const float4 s0 = ldh4(proj + r0 + c0);
      const float4 s1 = ldh4(proj + r1 + c0);
      float p0 = att_tanh_dot(s0, d4, a4, A);
      float p1 = att_tanh_dot(s1, d4, a4, A);
      p0 += __shfl_xor(p0, 4, 64);  p1 += __shfl_xor(p1, 4, 64);
      p0 += __shfl_xor(p0, 2, 64);  p1 += __shfl_xor(p1, 2, 64);
      p0 += __shfl_xor(p0, 1, 64);  p1 += __shfl_xor(p1, 1, 64);
      lm = fmaxf(lm, fmaxf(p0, p1));
      const float e0 = __expf(p0 - M0);
      const float e1 = __expf(p1 - M0);
      ax += s0.x * e0 + s1.x * e1;
      ay += s0.y * e0 + s1.y * e1;
      az += s0.z * e0 + s1.z * e1;
      aw += s0.w * e0 + s1.w * e1;
      dsum += e0 + e1;
      i += 4;
    }
    for (; i < end; i += 2) {
      const int idx = i + half;
      const bool valid = idx < end;
      const int row = rc[valid ? idx : i];
      const float4 s4 = ldh4(proj + row + c0);
      float p = att_tanh_dot(s4, d4, a4, A);
      p += __shfl_xor(p, 4, 64);
      p += __shfl_xor(p, 2, 64);
      p += __shfl_xor(p, 1, 64);
      if (!valid) p = -3.0e38f;
      lm = fmaxf(lm, p);
      const float e = __expf(p - M0);
      ax += s4.x * e; ay += s4.y * e; az += s4.z * e; aw += s4.w * e;
      dsum += e;
    }
    dsum += __shfl_xor(dsum, 32, 64);
    ax += __shfl_xor(ax, 32, 64);
    ay += __shfl_xor(ay, 32, 64);
    az += __shfl_xor(az, 32, 64);
    aw += __shfl_xor(aw, 32, 64);
    lm = fmaxf(lm, __shfl_xor(lm, 32, 64));
    if (half == 0) {
      const float inv = 1.f / fmaxf(dsum, 1e-38f);
      *(float4*)(out + (size_t)n * HC + c0) =
          make_float4(ax * inv, ay * inv, az * inv, aw * inv);
      if ((l & 7) == 0) den[n * HEADS + head] = dsum;
      if ((l & 7) == 0) atomicMax(&blkmax[head], flip_f32(lm));
    }
  }
  __syncthreads();
  if (tid < HEADS) {
    const unsigned v = blkmax[tid];
    if (v > headmax_u[tid]) atomicMax(&headmax_u[tid], v);
  }
}

// Reference normalizer = den * exp(M0_h - Mt_h). If below 1e-12 the reference
// clamps: out_ref = out_ours * (ref_den / 1e-12).
__global__ __launch_bounds__(256) void fix_clamp(float* __restrict__ out,
                                                 const float* __restrict__ den,
                                                 const unsigned* __restrict__ headmax_u,
                                                 const float* __restrict__ att, int N) {
  const int t = blockIdx.x * 256 + threadIdx.x;
  if (t >= N * HEADS) return;
  const int n = t >> 2;
  const int h = t & 3;
  float M0 = 0.f;
#pragma unroll
  for (int c = 0; c < OUT_CH; ++c) M0 += fabsf(att[h * OUT_CH + c]);
  const float Mt = unflip_f32(headmax_u[h]);
  const float f = den[t] * __expf(M0 - Mt);
  if (f < 1e-12f) {
    const float s = f * 1e12f;
    float4* p = (float4*)(out + (size_t)n * HC + h * OUT_CH);
#pragma unroll
    for (int j = 0; j < 8; ++j) {
      float4 v = p[j];
      v.x *= s; v.y *= s; v.z *= s; v.w *= s;
      p[j] = v;
    }
  }
}

// blockmax -> corr (fallback path only)
__global__ __launch_bounds__(256) void reduce_corr(const unsigned* __restrict__ blockmax,
                                                   const float* __restrict__ att,
                                                   float* __restrict__ corr, int nblk) {
  __shared__ unsigned sm[HEADS];
  const int tid = threadIdx.x;
  if (tid < HEADS) sm[tid] = 0u;
  __syncthreads();
  const int h = tid & 3;
  unsigned k = 0u;
  for (int i = tid >> 2; i < nblk; i += 64) k = max(k, blockmax[i * HEADS + h]);
  atomicMax(&sm[h], k);
  __syncthreads();
  if (tid < HEADS) {
    const float Mt = unflip_f32(sm[tid]);
    float M0 = 0.f;
#pragma unroll
    for (int c = 0; c < OUT_CH; ++c) M0 += fabsf(att[tid * OUT_CH + c]);
    corr[tid] = __expf(M0 - Mt);
    corr[4 + tid] = Mt;
  }
}

// --- fallback path (ws too small): score-max pass + edge-parallel atomics ---
__global__ __launch_bounds__(256) void score_max(const __half* __restrict__ proj,
                                                 const int* __restrict__ erow,
                                                 const int* __restrict__ ecol,
                                                 const float* __restrict__ att,
                                                 unsigned* __restrict__ blockmax, int E) {
  __shared__ unsigned blkmax[HEADS];
  const int tid = threadIdx.x;
  if (tid < HEADS) blkmax[tid] = 0u;
  __syncthreads();
  const int lane = tid & 63;
  const int wid = tid >> 6;
  const float a0 = att[lane];
  const float a1 = att[lane + 64];
  float lmA = -3.0e38f, lmB = -3.0e38f;
  const int stride = SCORE_BLOCKS * 16;

  for (int base = (blockIdx.x * 4 + wid) * 4; base < E; base += stride) {
    const int bu = __builtin_amdgcn_readfirstlane(base);
    const int lim = min(bu + 4, E);
    for (int e = bu; e < lim; ++e) {
      const int r0 = erow[e], c0 = ecol[e];
      const __half* ps = proj + (size_t)r0 * HC;
      const __half* pd = proj + (size_t)c0 * HC;
      float pA = fast_tanh(__half2float(ps[lane]) + __half2float(pd[lane])) * a0;
      float pB = fast_tanh(__half2float(ps[lane + 64]) + __half2float(pd[lane + 64])) * a1;
#pragma unroll
      for (int m = 16; m >= 1; m >>= 1) {
        pA += __shfl_xor(pA, m, 64);
        pB += __shfl_xor(pB, m, 64);
      }
      lmA = fmaxf(lmA, pA);
      lmB = fmaxf(lmB, pB);
    }
  }
  if ((lane & 31) == 0) {
    const int hh = lane >> 5;
    atomicMax(&blkmax[hh], flip_f32(lmA));
    atomicMax(&blkmax[hh + 2], flip_f32(lmB));
  }
  __syncthreads();
  if (tid < HEADS) blockmax[blockIdx.x * HEADS + tid] = blkmax[tid];
}

__global__ __launch_bounds__(256) void edge_apply_fb(const __half* __restrict__ proj,
                                                     const int* __restrict__ erow,
                                                     const int* __restrict__ ecol,
                                                     const float* __restrict__ att,
                                                     const float* __restrict__ headmax,
                                                     float* __restrict__ out,
                                                     float* __restrict__ norm, int E) {
  const int tid = threadIdx.x;
  const int e = blockIdx.x * 2 + (tid >> 7);
  if (e >= E) return;
  const int ch = tid & 127;
  const int h = ch >> 5;
  const float M = headmax[h];
  const int row = erow[e];
  const int col = ecol[e];
  const float sv = __half2float(proj[(size_t)row * HC + ch]);
  const float dv = __half2float(proj[(size_t)col * HC + ch]);
  float p = fast_tanh(sv + dv) * att[ch];
#pragma unroll
  for (int m = 16; m >= 1; m >>= 1) p += __shfl_xor(p, m, 64);
  const float w = __expf(p - M);
  unsafeAtomicAdd(&out[(size_t)col * HC + ch], sv * w);
  if ((ch & 31) == 0) unsafeAtomicAdd(&norm[(size_t)col * HEADS + h], w);
}

__global__ __launch_bounds__(256) void finalize_fb(float* __restrict__ out,
                                                   const float* __restrict__ norm, int N) {
  const int idx = blockIdx.x * blockDim.x + threadIdx.x;
  const int total = N * (HC / 4);
  if (idx >= total) return;
  const int base = idx * 4;
  const int node = base >> 7;
  const int h = (base >> 5) & 3;
  const float inv = 1.f / fmaxf(norm[node * HEADS + h], 1e-12f);
  float4 v = ((float4*)out)[idx];
  v.x *= inv; v.y *= inv; v.z *= inv; v.w *= inv;
  ((float4*)out)[idx] = v;
}

extern "C" void kernel_launch(void* const* d_in, const int* in_sizes, int n_in,
                              void* d_out, int out_size, void* d_ws, size_t ws_size,
                              hipStream_t stream) {
  const float* x    = (const float*)d_in[0];
  const int*   eidx = (const int*)d_in[1];  // [2][E]: row(src) then col(dst)
  const float* W    = (const float*)d_in[2];
  const float* att  = (const float*)d_in[3];
  float* out = (float*)d_out;

  const int N = in_sizes[0] / IN_CH;
  const int E = in_sizes[1] / 2;
  const int NB = (N + BW - 1) >> BW_SHIFT;  // buckets (<=1024 supported)
  const int ngemm = ((N + 63) / 64) * 2;    // 64-row x 64-col tiles

  // ws layout (16B-aligned pieces)
  char* p = (char*)d_ws;
  __half* proj = (__half*)p;  p += (((size_t)N * HC * 2 + 15) & ~15ull);
  int* rc = (int*)p;        p += (((size_t)E * 4 + 15) & ~15ull);
  float* den = (float*)p;   p += (((size_t)N * HEADS * 4 + 15) & ~15ull);
  int* small = (int*)p;     p += (((size_t)(2 * NB + 4 + NB + 1) * 4 + 15) & ~15ull);
  int* starts = (int*)p;    p += (((size_t)(N + 1) * 4 + 15) & ~15ull);
  int2* aux = (int2*)p;     p += (((size_t)E * 8 + 15) & ~15ull);
  int* bcnt0 = small;                  // [NB]   zeroed
  int* bcnt = small + NB;              // [NB]   zeroed
  unsigned* headmax_u = (unsigned*)(small + 2 * NB);  // [4] zeroed
  int* bstarts = small + 2 * NB + 4;   // [NB+1]
  const size_t need_full = (size_t)(p - (char*)d_ws);
  const bool full = (ws_size >= need_full) && (NB <= 1024);

  if (full) {
    hipMemsetAsync(small, 0, (size_t)(2 * NB + 4) * sizeof(int), stream);
    gemm_xW<<<ngemm, 256, 0, stream>>>(x, W, proj, N, eidx + E, bcnt0, E, NB);
    bucket_scan<<<1, 256, 0, stream>>>(bcnt0, bstarts, NB);
    bucket_split<<<(E + 2047) / 2048, 256, 0, stream>>>(eidx, eidx + E, bstarts,
                                                        bcnt, aux, E, NB);
    bucket_place<<<NB, 256, 0, stream>>>(aux, bstarts, starts, rc, N, NB);
    fused_apply<<<(N + 3) / 4, 256, 0, stream>>>(proj, rc, starts, att, out, den,
                                                 headmax_u, N);
    fix_clamp<<<(N * HEADS + 255) / 256, 256, 0, stream>>>(out, den, headmax_u, att, N);
  } else {
    // minimal-ws fallback: blockmax/corr/norm packed right after proj
    gemm_xW<<<ngemm, 256, 0, stream>>>(x, W, proj, N, nullptr, nullptr, 0, 0);
    unsigned* bm = (unsigned*)((char*)d_ws + (((size_t)N * HC * 2 + 15) & ~15ull));
    float* cr = (float*)(bm + SCORE_BLOCKS * HEADS);
    float* norm = cr + 8;
    hipMemsetAsync(out, 0, (size_t)out_size * sizeof(float), stream);
    hipMemsetAsync(norm, 0, (size_t)N * HEADS * sizeof(float), stream);
    score_max<<<SCORE_BLOCKS, 256, 0, stream>>>(proj, eidx, eidx + E, att, bm, E);
    reduce_corr<<<1, 256, 0, stream>>>(bm, att, cr, SCORE_BLOCKS);
    edge_apply_fb<<<(E + 1) / 2, 256, 0, stream>>>(proj, eidx, eidx + E, att, cr + 4, out, norm, E);
    finalize_fb<<<(N * (HC / 4) + 255) / 256, 256, 0, stream>>>(out, norm, N);
  }
}